// Round 9
// baseline (571.010 us; speedup 1.0000x reference)
//
#include <hip/hip_runtime.h>
#include <hip/hip_bf16.h>

// SchNet CFConv, MI355X gfx950 — round 12: ONE persistent fused kernel.
// r11 ledger: cfconv 73us, everything else 136us (prep+dreb kernel, in2f,
// f2out, ~3 launch gaps). All stages are strictly dependent -> fuse into one
// persistent kernel with device-wide barriers (atomic counter, agent scope,
// acquire/release — the cooperative grid.sync pattern):
//   phase0: weight transposes (W1T/W2T/WiT/WoT) + dreb transform (grid-stride)
//   bar0
//   phase1: in2f yfeatb = bf16(x @ Wi)  (r1-proven global-WiT MFMA, no LDS)
//   bar1
//   phase2: r11 cfconv_pp pipelined loop VERBATIM (73us proven), stride=grid
//   bar2
//   phase3: f2out in-place on out (r1-proven)
// Safety: grid sized from hipOccupancyMaxActiveBlocksPerMultiprocessor (host
// query, capture-safe) so all blocks are guaranteed co-resident; bounded spin
// (fails visibly, never hangs); barrier counters memset each launch (replay-
// safe). ws gated >= 33386752 B; fallback = exact r11 3-kernel path (its
// 33353728 B requirement proven in r8/r11).
//
// FUSED d_ws layout (unsigned short elements):
//   [0        .. 4096    )  W1T  bf16 [128 f][32 gpad]  (g>=25 zero)
//   [4096     .. 20480   )  W2T  bf16 [128 h][128 j]
//   [20480    .. 36864   )  WiT  bf16 [128 f][128 i]
//   [36864    .. 53248   )  WoT  bf16 [128 o][128 f]
//   [53248    .. 1333248 )  yfeatb bf16 [10000][128]
//   [1333248  .. 16693248)  dreb bf16 [10000][48][32]
//   [16693248 .. +128    )  barrier counters (u32), memset per launch

#define NA 10000
#define NK 48
#define NF 128
#define HP  136   // s_H  row pad (bf16): 272 B rows -> 2-way (free)
#define YFP 136   // s_yf row pad (bf16)

typedef __bf16 bf16x8 __attribute__((ext_vector_type(8)));
typedef float  f32x4  __attribute__((ext_vector_type(4)));

__device__ __forceinline__ unsigned short f2bs(float x) {
    return __builtin_bit_cast(unsigned short, (__bf16)x);
}
__device__ __forceinline__ float bs2f(unsigned short u) {
    return (float)__builtin_bit_cast(__bf16, u);
}
__device__ __forceinline__ float sspf(float v) {
    return fmaxf(v, 0.0f) + __logf(1.0f + __expf(-fabsf(v))) - 0.69314718056f;
}

// ---- device-wide barrier: distinct counter per use, memset'd per launch ----
__device__ __forceinline__ void gridbar(unsigned int* cnt, unsigned int target) {
    __syncthreads();
    if (threadIdx.x == 0) {
        __threadfence();   // make this block's prior writes device-visible
        __hip_atomic_fetch_add(cnt, 1u, __ATOMIC_ACQ_REL, __HIP_MEMORY_SCOPE_AGENT);
        unsigned int guard = 0;
        while (__hip_atomic_load(cnt, __ATOMIC_ACQUIRE, __HIP_MEMORY_SCOPE_AGENT) < target) {
            if (++guard > 100000000u) break;   // fail visibly, never hang
            __builtin_amdgcn_s_sleep(2);
        }
        __threadfence();
    }
    __syncthreads();
}

// ==================== fused persistent kernel ====================
__global__ __launch_bounds__(256, 4) void cfconv_fused(
    const float* __restrict__ x,
    const float* __restrict__ dR,
    const float* __restrict__ dRe,
    const float* __restrict__ mask,
    const int*   __restrict__ nbr,
    const float* __restrict__ b1,
    const float* __restrict__ b2,
    const float* __restrict__ W1,
    const float* __restrict__ W2,
    const float* __restrict__ Wi,
    const float* __restrict__ Wo,
    const float* __restrict__ bf2o,
    unsigned short* __restrict__ wsb,
    unsigned short* __restrict__ yfeatb,
    unsigned short* __restrict__ dreb,
    unsigned int* bar,
    float* __restrict__ out)
{
    __shared__ __align__(16) unsigned short s_H[NK * HP];    // 13056 B
    __shared__ __align__(16) unsigned short s_yf[NK * YFP];  // 13056 B
    __shared__ float s_cm[NK];                               // 192 B

    const int tid  = threadIdx.x;
    const int bid  = blockIdx.x;
    const int nblk = gridDim.x;
    const unsigned int NB = (unsigned int)nblk;

    const int w = tid >> 6;
    const int lane = tid & 63;
    const int r = lane & 15;
    const int q = lane >> 4;
    const int nt0 = w * 2;
    const int kb = tid >> 4;
    const int sp = tid & 15;

    const unsigned short* W1T = wsb;
    const unsigned short* W2T = wsb + 4096;
    const unsigned short* WiT = wsb + 20480;
    const unsigned short* WoT = wsb + 36864;

    // ---------------- phase 0: weight transposes + dreb transform ----------------
    {
        int i = bid * 256 + tid;
        if (i < 4096) {                       // W1T[f][g], g padded to 32
            int f = i >> 5, g = i & 31;
            wsb[i] = (g < 25) ? f2bs(W1[g * NF + f]) : (unsigned short)0;
        } else if (i < 20480) {               // W2T[h][j]
            int j = i - 4096; int h = j >> 7, k = j & 127;
            wsb[i] = f2bs(W2[k * NF + h]);
        } else if (i < 36864) {               // WiT[f][i]
            int j = i - 20480; int f = j >> 7, k = j & 127;
            wsb[i] = f2bs(Wi[k * NF + f]);
        } else if (i < 53248) {               // WoT[o][f]
            int j = i - 36864; int f = j >> 7, k = j & 127;
            wsb[i] = f2bs(Wo[k * NF + f]);
        }

        // dreb transform (r8-proven body), grid-stride over all blocks
        const float4* src = (const float4*)dRe;
        for (int j = bid * 256 + tid; j < 3000000; j += nblk * 256) {
            float4 v = src[j];
            int n  = j / 300;
            int rm = j - n * 300;
            int i2 = rm * 4;
            int k  = i2 / 25;
            int g  = i2 - k * 25;
            unsigned short* dst = dreb + (size_t)n * 1536;
            float vv[4] = {v.x, v.y, v.z, v.w};
            #pragma unroll
            for (int e = 0; e < 4; ++e) {
                dst[k * 32 + g] = f2bs(vv[e]);
                if (++g == 25) {
                    #pragma unroll
                    for (int p = 25; p < 32; ++p) dst[k * 32 + p] = 0;
                    g = 0; ++k;
                }
            }
        }
    }
    gridbar(bar + 0, NB);

    // ---------------- phase 1: in2f (r1-proven global-WiT MFMA) ----------------
    for (int tile = bid; tile < 157; tile += nblk) {
        const int m0 = tile * 64 + w * 16;
        const int row = m0 + r;
        const bool rv = (row < NA);

        f32x4 acc[8];
        #pragma unroll
        for (int nt = 0; nt < 8; ++nt) { acc[nt][0]=0.f; acc[nt][1]=0.f; acc[nt][2]=0.f; acc[nt][3]=0.f; }

        #pragma unroll
        for (int ks = 0; ks < 4; ++ks) {
            bf16x8 a;
            if (rv) {
                const float4* xp = (const float4*)(x + (size_t)row * NF + ks * 32 + q * 8);
                float4 v0 = xp[0], v1 = xp[1];
                a[0]=(__bf16)v0.x; a[1]=(__bf16)v0.y; a[2]=(__bf16)v0.z; a[3]=(__bf16)v0.w;
                a[4]=(__bf16)v1.x; a[5]=(__bf16)v1.y; a[6]=(__bf16)v1.z; a[7]=(__bf16)v1.w;
            } else {
                #pragma unroll
                for (int j = 0; j < 8; ++j) a[j] = (__bf16)0.0f;
            }
            #pragma unroll
            for (int nt = 0; nt < 8; ++nt) {
                bf16x8 b = *(const bf16x8*)(WiT + (nt * 16 + r) * NF + ks * 32 + q * 8);
                acc[nt] = __builtin_amdgcn_mfma_f32_16x16x32_bf16(a, b, acc[nt], 0, 0, 0);
            }
        }
        #pragma unroll
        for (int nt = 0; nt < 8; ++nt) {
            #pragma unroll
            for (int reg = 0; reg < 4; ++reg) {
                int orow = m0 + q * 4 + reg;
                if (orow < NA)
                    yfeatb[(size_t)orow * NF + nt * 16 + r] = f2bs(acc[nt][reg]);
            }
        }
    }
    gridbar(bar + 1, NB);

    // ---------------- phase 2: pipelined cfconv (r11 verbatim, stride nblk) ----------------
    {
        const bf16x8 bfr0 = *(const bf16x8*)(W1T + ((nt0    ) * 16 + r) * 32 + q * 8);
        const bf16x8 bfr1 = *(const bf16x8*)(W1T + ((nt0 + 1) * 16 + r) * 32 + q * 8);
        bf16x8 bw[2][4];
        #pragma unroll
        for (int t = 0; t < 2; ++t)
            #pragma unroll
            for (int ks = 0; ks < 4; ++ks)
                bw[t][ks] = *(const bf16x8*)(W2T + ((nt0 + t) * 16 + r) * NF + ks * 32 + q * 8);
        const float bias1a = b1[nt0 * 16 + r];
        const float bias1b = b1[nt0 * 16 + 16 + r];
        const float bias2a = b2[nt0 * 16 + r];
        const float bias2b = b2[nt0 * 16 + 16 + r];

        bf16x8 g0, g1, g2;
        bf16x8 a0, a1, a2;
        float dv = 10.0f, mv = 0.0f;
        unsigned short hsv[24];

        auto prefetch = [&](int nn) {
            const int nb0 = nbr[nn * NK + kb] * NF;
            const int nb1 = nbr[nn * NK + kb + 16] * NF;
            const int nb2 = nbr[nn * NK + kb + 32] * NF;
            g0 = *(const bf16x8*)(yfeatb + nb0 + sp * 8);
            g1 = *(const bf16x8*)(yfeatb + nb1 + sp * 8);
            g2 = *(const bf16x8*)(yfeatb + nb2 + sp * 8);
            const unsigned short* dn = dreb + (size_t)nn * 1536;
            a0 = *(const bf16x8*)(dn + (     r) * 32 + q * 8);
            a1 = *(const bf16x8*)(dn + (16 + r) * 32 + q * 8);
            a2 = *(const bf16x8*)(dn + (32 + r) * 32 + q * 8);
            if (tid < NK) {
                dv = dR[nn * NK + tid];
                mv = mask[nn * NK + tid];
            }
        };

        auto stage1 = [&]() {
            #pragma unroll
            for (int mt = 0; mt < 3; ++mt) {
                bf16x8 av8 = (mt == 0) ? a0 : (mt == 1) ? a1 : a2;
                f32x4 zf; zf[0]=0.f; zf[1]=0.f; zf[2]=0.f; zf[3]=0.f;
                f32x4 h0v = __builtin_amdgcn_mfma_f32_16x16x32_bf16(av8, bfr0, zf, 0, 0, 0);
                f32x4 h1v = __builtin_amdgcn_mfma_f32_16x16x32_bf16(av8, bfr1, zf, 0, 0, 0);
                #pragma unroll
                for (int reg = 0; reg < 4; ++reg) {
                    hsv[mt * 8 + reg]     = f2bs(sspf(h0v[reg] + bias1a));
                    hsv[mt * 8 + 4 + reg] = f2bs(sspf(h1v[reg] + bias1b));
                }
            }
        };

        auto ldswrite = [&]() {
            #pragma unroll
            for (int mt = 0; mt < 3; ++mt) {
                #pragma unroll
                for (int reg = 0; reg < 4; ++reg) {
                    int k = mt * 16 + q * 4 + reg;
                    s_H[k * HP + nt0 * 16 + r]      = hsv[mt * 8 + reg];
                    s_H[k * HP + nt0 * 16 + 16 + r] = hsv[mt * 8 + 4 + reg];
                }
            }
            *(bf16x8*)(&s_yf[(kb     ) * YFP + sp * 8]) = g0;
            *(bf16x8*)(&s_yf[(kb + 16) * YFP + sp * 8]) = g1;
            *(bf16x8*)(&s_yf[(kb + 32) * YFP + sp * 8]) = g2;
            if (tid < NK)
                s_cm[tid] = (dv <= 5.0f) ? mv : 0.0f;
        };

        int n = bid;
        prefetch(n);
        stage1();
        ldswrite();
        __syncthreads();

        while (true) {
            const int n_next = n + nblk;
            const bool more = (n_next < NA);

            if (more) prefetch(n_next);

            f32x4 acc[3][2];
            #pragma unroll
            for (int mt = 0; mt < 3; ++mt)
                #pragma unroll
                for (int t = 0; t < 2; ++t) { acc[mt][t][0]=0.f; acc[mt][t][1]=0.f; acc[mt][t][2]=0.f; acc[mt][t][3]=0.f; }

            #pragma unroll
            for (int ks = 0; ks < 4; ++ks) {
                #pragma unroll
                for (int mt = 0; mt < 3; ++mt) {
                    bf16x8 ah = *(const bf16x8*)(&s_H[(mt * 16 + r) * HP + ks * 32 + q * 8]);
                    acc[mt][0] = __builtin_amdgcn_mfma_f32_16x16x32_bf16(ah, bw[0][ks], acc[mt][0], 0, 0, 0);
                    acc[mt][1] = __builtin_amdgcn_mfma_f32_16x16x32_bf16(ah, bw[1][ks], acc[mt][1], 0, 0, 0);
                }
            }

            if (more) stage1();

            float part0 = 0.f, part1 = 0.f;
            const int h0 = nt0 * 16 + r;
            #pragma unroll
            for (int mt = 0; mt < 3; ++mt) {
                #pragma unroll
                for (int reg = 0; reg < 4; ++reg) {
                    int k = mt * 16 + q * 4 + reg;
                    float cmk = s_cm[k];
                    part0 += cmk * (acc[mt][0][reg] + bias2a) * bs2f(s_yf[k * YFP + h0]);
                    part1 += cmk * (acc[mt][1][reg] + bias2b) * bs2f(s_yf[k * YFP + h0 + 16]);
                }
            }
            part0 += __shfl_xor(part0, 16);
            part0 += __shfl_xor(part0, 32);
            part1 += __shfl_xor(part1, 16);
            part1 += __shfl_xor(part1, 32);
            if (q == 0) {
                out[(size_t)n * NF + h0]      = part0;
                out[(size_t)n * NF + h0 + 16] = part1;
            }

            if (!more) break;

            __syncthreads();
            ldswrite();
            __syncthreads();
            n = n_next;
        }
    }
    gridbar(bar + 2, NB);

    // ---------------- phase 3: f2out in-place (r1-proven) ----------------
    for (int tile = bid; tile < 157; tile += nblk) {
        const int m0 = tile * 64 + w * 16;
        const int row = m0 + r;
        const bool rv = (row < NA);

        f32x4 acc[8];
        #pragma unroll
        for (int nt = 0; nt < 8; ++nt) { acc[nt][0]=0.f; acc[nt][1]=0.f; acc[nt][2]=0.f; acc[nt][3]=0.f; }

        #pragma unroll
        for (int ks = 0; ks < 4; ++ks) {
            bf16x8 a;
            if (rv) {
                const float4* yp = (const float4*)(out + (size_t)row * NF + ks * 32 + q * 8);
                float4 v0 = yp[0], v1 = yp[1];
                a[0]=(__bf16)v0.x; a[1]=(__bf16)v0.y; a[2]=(__bf16)v0.z; a[3]=(__bf16)v0.w;
                a[4]=(__bf16)v1.x; a[5]=(__bf16)v1.y; a[6]=(__bf16)v1.z; a[7]=(__bf16)v1.w;
            } else {
                #pragma unroll
                for (int j = 0; j < 8; ++j) a[j] = (__bf16)0.0f;
            }
            #pragma unroll
            for (int nt = 0; nt < 8; ++nt) {
                bf16x8 b = *(const bf16x8*)(WoT + (nt * 16 + r) * NF + ks * 32 + q * 8);
                acc[nt] = __builtin_amdgcn_mfma_f32_16x16x32_bf16(a, b, acc[nt], 0, 0, 0);
            }
        }
        #pragma unroll
        for (int nt = 0; nt < 8; ++nt) {
            float bia = bf2o[nt * 16 + r];
            #pragma unroll
            for (int reg = 0; reg < 4; ++reg) {
                int orow = m0 + q * 4 + reg;
                if (orow < NA)
                    out[(size_t)orow * NF + nt * 16 + r] = sspf(acc[nt][reg] + bia);
            }
        }
    }
}

// ==================== fallback path: exact r11 3-kernel config ====================

__global__ __launch_bounds__(256) void in2f_prep_fb(
    const float* __restrict__ x,
    const float* __restrict__ Wi,
    const float* __restrict__ W1,
    const float* __restrict__ W2,
    const float* __restrict__ Wo,
    const float* __restrict__ dRe,
    unsigned short* __restrict__ wsb,
    unsigned short* __restrict__ yfeatb,
    unsigned short* __restrict__ dreb)
{
    const int tid = threadIdx.x;

    if (blockIdx.x >= 301) {
        const float4* src = (const float4*)dRe;
        for (int j = (blockIdx.x - 301) * 256 + tid; j < 3000000; j += 768 * 256) {
            float4 v = src[j];
            int n  = j / 300;
            int rm = j - n * 300;
            int i  = rm * 4;
            int k  = i / 25;
            int g  = i - k * 25;
            unsigned short* dst = dreb + (size_t)n * 1536;
            float vv[4] = {v.x, v.y, v.z, v.w};
            #pragma unroll
            for (int e = 0; e < 4; ++e) {
                dst[k * 32 + g] = f2bs(vv[e]);
                if (++g == 25) {
                    #pragma unroll
                    for (int p = 25; p < 32; ++p) dst[k * 32 + p] = 0;
                    g = 0; ++k;
                }
            }
        }
        return;
    }

    if (blockIdx.x >= 157) {
        int i = (blockIdx.x - 157) * 256 + tid;
        if (i < 4096) {
            int f = i >> 5, g = i & 31;
            wsb[i] = (g < 25) ? f2bs(W1[g * NF + f]) : (unsigned short)0;
        } else if (i < 20480) {
            int j = i - 4096; int h = j >> 7, k = j & 127;
            wsb[i] = f2bs(W2[k * NF + h]);
        } else {
            int j = i - 20480; int f = j >> 7, k = j & 127;
            wsb[i] = f2bs(Wo[k * NF + f]);
        }
        return;
    }

    __shared__ __align__(16) unsigned short s_wi[NF * 136];
    {
        const float4* wi4 = (const float4*)Wi;
        #pragma unroll
        for (int it = 0; it < 16; ++it) {
            int idx4 = it * 256 + tid;
            float4 v = wi4[idx4];
            int i = idx4 >> 5;
            int f = (idx4 & 31) * 4;
            s_wi[(f + 0) * 136 + i] = f2bs(v.x);
            s_wi[(f + 1) * 136 + i] = f2bs(v.y);
            s_wi[(f + 2) * 136 + i] = f2bs(v.z);
            s_wi[(f + 3) * 136 + i] = f2bs(v.w);
        }
    }
    __syncthreads();

    const int w = tid >> 6;
    const int lane = tid & 63;
    const int r = lane & 15;
    const int q = lane >> 4;
    const int m0 = blockIdx.x * 64 + w * 16;
    const int row = m0 + r;
    const bool rv = (row < NA);

    f32x4 acc[8];
    #pragma unroll
    for (int nt = 0; nt < 8; ++nt) { acc[nt][0]=0.f; acc[nt][1]=0.f; acc[nt][2]=0.f; acc[nt][3]=0.f; }

    #pragma unroll
    for (int ks = 0; ks < 4; ++ks) {
        bf16x8 a;
        if (rv) {
            const float4* xp = (const float4*)(x + (size_t)row * NF + ks * 32 + q * 8);
            float4 v0 = xp[0], v1 = xp[1];
            a[0]=(__bf16)v0.x; a[1]=(__bf16)v0.y; a[2]=(__bf16)v0.z; a[3]=(__bf16)v0.w;
            a[4]=(__bf16)v1.x; a[5]=(__bf16)v1.y; a[6]=(__bf16)v1.z; a[7]=(__bf16)v1.w;
        } else {
            #pragma unroll
            for (int j = 0; j < 8; ++j) a[j] = (__bf16)0.0f;
        }
        #pragma unroll
        for (int nt = 0; nt < 8; ++nt) {
            bf16x8 b = *(const bf16x8*)(&s_wi[(nt * 16 + r) * 136 + ks * 32 + q * 8]);
            acc[nt] = __builtin_amdgcn_mfma_f32_16x16x32_bf16(a, b, acc[nt], 0, 0, 0);
        }
    }
    #pragma unroll
    for (int nt = 0; nt < 8; ++nt) {
        #pragma unroll
        for (int reg = 0; reg < 4; ++reg) {
            int orow = m0 + q * 4 + reg;
            if (orow < NA)
                yfeatb[(size_t)orow * NF + nt * 16 + r] = f2bs(acc[nt][reg]);
        }
    }
}

__global__ __launch_bounds__(256, 4) void cfconv_pp_fb(
    const float* __restrict__ dR,
    const float* __restrict__ mask,
    const int*   __restrict__ nbr,
    const float* __restrict__ b1,
    const float* __restrict__ b2,
    const unsigned short* __restrict__ W1T,
    const unsigned short* __restrict__ W2T,
    const unsigned short* __restrict__ dreb,
    const unsigned short* __restrict__ yfeatb,
    float* __restrict__ yout)
{
    __shared__ __align__(16) unsigned short s_H[NK * HP];
    __shared__ __align__(16) unsigned short s_yf[NK * YFP];
    __shared__ float s_cm[NK];

    const int tid = threadIdx.x;
    const int w = tid >> 6;
    const int lane = tid & 63;
    const int r = lane & 15;
    const int q = lane >> 4;
    const int nt0 = w * 2;
    const int kb = tid >> 4;
    const int sp = tid & 15;

    const bf16x8 bfr0 = *(const bf16x8*)(W1T + ((nt0    ) * 16 + r) * 32 + q * 8);
    const bf16x8 bfr1 = *(const bf16x8*)(W1T + ((nt0 + 1) * 16 + r) * 32 + q * 8);
    bf16x8 bw[2][4];
    #pragma unroll
    for (int t = 0; t < 2; ++t)
        #pragma unroll
        for (int ks = 0; ks < 4; ++ks)
            bw[t][ks] = *(const bf16x8*)(W2T + ((nt0 + t) * 16 + r) * NF + ks * 32 + q * 8);
    const float bias1a = b1[nt0 * 16 + r];
    const float bias1b = b1[nt0 * 16 + 16 + r];
    const float bias2a = b2[nt0 * 16 + r];
    const float bias2b = b2[nt0 * 16 + 16 + r];

    bf16x8 g0, g1, g2, a0, a1, a2;
    float dv = 10.0f, mv = 0.0f;
    unsigned short hsv[24];

    auto prefetch = [&](int nn) {
        const int nb0 = nbr[nn * NK + kb] * NF;
        const int nb1 = nbr[nn * NK + kb + 16] * NF;
        const int nb2 = nbr[nn * NK + kb + 32] * NF;
        g0 = *(const bf16x8*)(yfeatb + nb0 + sp * 8);
        g1 = *(const bf16x8*)(yfeatb + nb1 + sp * 8);
        g2 = *(const bf16x8*)(yfeatb + nb2 + sp * 8);
        const unsigned short* dn = dreb + (size_t)nn * 1536;
        a0 = *(const bf16x8*)(dn + (     r) * 32 + q * 8);
        a1 = *(const bf16x8*)(dn + (16 + r) * 32 + q * 8);
        a2 = *(const bf16x8*)(dn + (32 + r) * 32 + q * 8);
        if (tid < NK) { dv = dR[nn * NK + tid]; mv = mask[nn * NK + tid]; }
    };
    auto stage1 = [&]() {
        #pragma unroll
        for (int mt = 0; mt < 3; ++mt) {
            bf16x8 av8 = (mt == 0) ? a0 : (mt == 1) ? a1 : a2;
            f32x4 zf; zf[0]=0.f; zf[1]=0.f; zf[2]=0.f; zf[3]=0.f;
            f32x4 h0v = __builtin_amdgcn_mfma_f32_16x16x32_bf16(av8, bfr0, zf, 0, 0, 0);
            f32x4 h1v = __builtin_amdgcn_mfma_f32_16x16x32_bf16(av8, bfr1, zf, 0, 0, 0);
            #pragma unroll
            for (int reg = 0; reg < 4; ++reg) {
                hsv[mt * 8 + reg]     = f2bs(sspf(h0v[reg] + bias1a));
                hsv[mt * 8 + 4 + reg] = f2bs(sspf(h1v[reg] + bias1b));
            }
        }
    };
    auto ldswrite = [&]() {
        #pragma unroll
        for (int mt = 0; mt < 3; ++mt)
            #pragma unroll
            for (int reg = 0; reg < 4; ++reg) {
                int k = mt * 16 + q * 4 + reg;
                s_H[k * HP + nt0 * 16 + r]      = hsv[mt * 8 + reg];
                s_H[k * HP + nt0 * 16 + 16 + r] = hsv[mt * 8 + 4 + reg];
            }
        *(bf16x8*)(&s_yf[(kb     ) * YFP + sp * 8]) = g0;
        *(bf16x8*)(&s_yf[(kb + 16) * YFP + sp * 8]) = g1;
        *(bf16x8*)(&s_yf[(kb + 32) * YFP + sp * 8]) = g2;
        if (tid < NK) s_cm[tid] = (dv <= 5.0f) ? mv : 0.0f;
    };

    int n = blockIdx.x;
    prefetch(n); stage1(); ldswrite();
    __syncthreads();

    while (true) {
        const int n_next = n + 1024;
        const bool more = (n_next < NA);
        if (more) prefetch(n_next);

        f32x4 acc[3][2];
        #pragma unroll
        for (int mt = 0; mt < 3; ++mt)
            #pragma unroll
            for (int t = 0; t < 2; ++t) { acc[mt][t][0]=0.f; acc[mt][t][1]=0.f; acc[mt][t][2]=0.f; acc[mt][t][3]=0.f; }

        #pragma unroll
        for (int ks = 0; ks < 4; ++ks)
            #pragma unroll
            for (int mt = 0; mt < 3; ++mt) {
                bf16x8 ah = *(const bf16x8*)(&s_H[(mt * 16 + r) * HP + ks * 32 + q * 8]);
                acc[mt][0] = __builtin_amdgcn_mfma_f32_16x16x32_bf16(ah, bw[0][ks], acc[mt][0], 0, 0, 0);
                acc[mt][1] = __builtin_amdgcn_mfma_f32_16x16x32_bf16(ah, bw[1][ks], acc[mt][1], 0, 0, 0);
            }

        if (more) stage1();

        float part0 = 0.f, part1 = 0.f;
        const int h0 = nt0 * 16 + r;
        #pragma unroll
        for (int mt = 0; mt < 3; ++mt)
            #pragma unroll
            for (int reg = 0; reg < 4; ++reg) {
                int k = mt * 16 + q * 4 + reg;
                float cmk = s_cm[k];
                part0 += cmk * (acc[mt][0][reg] + bias2a) * bs2f(s_yf[k * YFP + h0]);
                part1 += cmk * (acc[mt][1][reg] + bias2b) * bs2f(s_yf[k * YFP + h0 + 16]);
            }
        part0 += __shfl_xor(part0, 16);
        part0 += __shfl_xor(part0, 32);
        part1 += __shfl_xor(part1, 16);
        part1 += __shfl_xor(part1, 32);
        if (q == 0) {
            yout[(size_t)n * NF + h0]      = part0;
            yout[(size_t)n * NF + h0 + 16] = part1;
        }

        if (!more) break;
        __syncthreads();
        ldswrite();
        __syncthreads();
        n = n_next;
    }
}

__global__ __launch_bounds__(256) void f2out_mfma_fb(
    const unsigned short* __restrict__ WoT,
    const float* __restrict__ bo,
    float* io)
{
    const int tid = threadIdx.x;
    const int w = tid >> 6;
    const int lane = tid & 63;
    const int r = lane & 15;
    const int q = lane >> 4;
    const int m0 = blockIdx.x * 64 + w * 16;
    const int row = m0 + r;
    const bool rv = (row < NA);

    f32x4 acc[8];
    #pragma unroll
    for (int nt = 0; nt < 8; ++nt) { acc[nt][0]=0.f; acc[nt][1]=0.f; acc[nt][2]=0.f; acc[nt][3]=0.f; }

    #pragma unroll
    for (int ks = 0; ks < 4; ++ks) {
        bf16x8 a;
        if (rv) {
            const float4* yp = (const float4*)(io + (size_t)row * NF + ks * 32 + q * 8);
            float4 v0 = yp[0], v1 = yp[1];
            a[0]=(__bf16)v0.x; a[1]=(__bf16)v0.y; a[2]=(__bf16)v0.z; a[3]=(__bf16)v0.w;
            a[4]=(__bf16)v1.x; a[5]=(__bf16)v1.y; a[6]=(__bf16)v1.z; a[7]=(__bf16)v1.w;
        } else {
            #pragma unroll
            for (int j = 0; j < 8; ++j) a[j] = (__bf16)0.0f;
        }
        #pragma unroll
        for (int nt = 0; nt < 8; ++nt) {
            bf16x8 b = *(const bf16x8*)(WoT + (nt * 16 + r) * NF + ks * 32 + q * 8);
            acc[nt] = __builtin_amdgcn_mfma_f32_16x16x32_bf16(a, b, acc[nt], 0, 0, 0);
        }
    }
    #pragma unroll
    for (int nt = 0; nt < 8; ++nt) {
        float bia = bo[nt * 16 + r];
        #pragma unroll
        for (int reg = 0; reg < 4; ++reg) {
            int orow = m0 + q * 4 + reg;
            if (orow < NA)
                io[(size_t)orow * NF + nt * 16 + r] = sspf(acc[nt][reg] + bia);
        }
    }
}

extern "C" void kernel_launch(void* const* d_in, const int* in_sizes, int n_in,
                              void* d_out, int out_size, void* d_ws, size_t ws_size,
                              hipStream_t stream)
{
    const float* x    = (const float*)d_in[0];
    const float* dR   = (const float*)d_in[1];
    const float* dRe  = (const float*)d_in[2];
    const float* mask = (const float*)d_in[3];
    const int*   nbr  = (const int*)d_in[4];
    const float* W1   = (const float*)d_in[5];
    const float* b1   = (const float*)d_in[6];
    const float* W2   = (const float*)d_in[7];
    const float* b2   = (const float*)d_in[8];
    const float* Wi2f = (const float*)d_in[9];
    const float* Wf2o = (const float*)d_in[10];
    const float* bf2o = (const float*)d_in[11];
    float* out = (float*)d_out;

    unsigned short* wsb = (unsigned short*)d_ws;

    // ---- fused path: needs 33386752 B (layout + 128 B barrier counters) ----
    bool fused_ok = ws_size >= 33386752ULL;
    int occ = 0;
    if (fused_ok) {
        if (hipOccupancyMaxActiveBlocksPerMultiprocessor(&occ, cfconv_fused, 256, 0) != hipSuccess)
            occ = 0;
        if (occ < 1) fused_ok = false;
    }

    if (fused_ok) {
        unsigned short* yfb  = wsb + 53248;     // 1,280,000 elems
        unsigned short* dreb = wsb + 1333248;   // 15,360,000 elems
        unsigned int*   bar  = (unsigned int*)(wsb + 16693248);
        int bpc  = occ > 6 ? 6 : occ;           // LDS cap is 6 blocks/CU
        int grid = bpc * 256;
        if (grid > 1536) grid = 1536;
        hipMemsetAsync(bar, 0, 128, stream);
        cfconv_fused<<<grid, 256, 0, stream>>>(x, dR, dRe, mask, nbr, b1, b2,
                                               W1, W2, Wi2f, Wf2o, bf2o,
                                               wsb, yfb, dreb, bar, out);
    } else {
        // ---- fallback: exact r11 3-kernel config (ws >= 33353728 proven) ----
        unsigned short* W1T    = wsb;
        unsigned short* W2T    = wsb + 4096;
        unsigned short* WoT    = wsb + 20480;
        unsigned short* yfeatb = wsb + 36864;
        unsigned short* dreb   = wsb + 1316864;
        in2f_prep_fb<<<1069, 256, 0, stream>>>(x, Wi2f, W1, W2, Wf2o, dRe,
                                               wsb, yfeatb, dreb);
        cfconv_pp_fb<<<1024, 256, 0, stream>>>(dR, mask, nbr, b1, b2,
                                               W1T, W2T, dreb, yfeatb, out);
        f2out_mfma_fb<<<157, 256, 0, stream>>>(WoT, bf2o, out);
    }
}

// Round 10
// 435.808 us; speedup vs baseline: 1.3102x; 1.3102x over previous
//
#include <hip/hip_runtime.h>
#include <hip/hip_bf16.h>

// SchNet CFConv, MI355X gfx950 — round 13: fused persistent kernel with FIXED
// grid barrier. r12's 899us failure: the spin used ACQUIRE at agent scope,
// which on gfx94x+ emits an L2 INVALIDATE PER POLL (per-XCD L2s non-coherent)
// -> spinning blocks continuously invalidated the device's caches while
// working blocks computed (WRITE_SIZE 118MB, 230GB/s thrash, VALU 5%).
// Fix: RELAXED spin (no cache op per poll) + ONE release fence before the
// increment + ONE acquire fence after spin exit (fence-to-fence sync through
// the relaxed atomic). Everything else byte-identical to r12 (phases are
// r11/r1-proven; r12 passed correctness, so the protocol is sound).
//
//   phase0: weight transposes (W1T/W2T/WiT/WoT) + dreb transform (grid-stride)
//   bar0
//   phase1: in2f yfeatb = bf16(x @ Wi)  (r1-proven global-WiT MFMA)
//   bar1
//   phase2: r11 cfconv_pp pipelined loop (73us proven), stride=grid
//   bar2
//   phase3: f2out in-place on out (r1-proven)
//
// FUSED d_ws layout (unsigned short elements):
//   [0        .. 4096    )  W1T  bf16 [128 f][32 gpad]  (g>=25 zero)
//   [4096     .. 20480   )  W2T  bf16 [128 h][128 j]
//   [20480    .. 36864   )  WiT  bf16 [128 f][128 i]
//   [36864    .. 53248   )  WoT  bf16 [128 o][128 f]
//   [53248    .. 1333248 )  yfeatb bf16 [10000][128]
//   [1333248  .. 16693248)  dreb bf16 [10000][48][32]
//   [16693248 .. +128    )  barrier counters (u32), memset per launch

#define NA 10000
#define NK 48
#define NF 128
#define HP  136   // s_H  row pad (bf16): 272 B rows -> 2-way (free)
#define YFP 136   // s_yf row pad (bf16)

typedef __bf16 bf16x8 __attribute__((ext_vector_type(8)));
typedef float  f32x4  __attribute__((ext_vector_type(4)));

__device__ __forceinline__ unsigned short f2bs(float x) {
    return __builtin_bit_cast(unsigned short, (__bf16)x);
}
__device__ __forceinline__ float bs2f(unsigned short u) {
    return (float)__builtin_bit_cast(__bf16, u);
}
__device__ __forceinline__ float sspf(float v) {
    return fmaxf(v, 0.0f) + __logf(1.0f + __expf(-fabsf(v))) - 0.69314718056f;
}

// ---- device-wide barrier, RELAXED spin (the r12 fix) ----
__device__ __forceinline__ void gridbar(unsigned int* cnt, unsigned int target) {
    __syncthreads();
    if (threadIdx.x == 0) {
        __threadfence();   // release (ONE L2 writeback), pairs with readers' acquire
        __hip_atomic_fetch_add(cnt, 1u, __ATOMIC_RELAXED, __HIP_MEMORY_SCOPE_AGENT);
        unsigned int guard = 0;
        // RELAXED poll: reads the coherent point, NO per-iteration cache inv.
        while (__hip_atomic_load(cnt, __ATOMIC_RELAXED, __HIP_MEMORY_SCOPE_AGENT) < target) {
            if (++guard > 4000000u) break;   // fail visibly, never hang (~0.1s cap)
            __builtin_amdgcn_s_sleep(8);
        }
        __threadfence();   // acquire (ONE L2 invalidate): other blocks' writes visible
    }
    __syncthreads();
}

// ==================== fused persistent kernel ====================
__global__ __launch_bounds__(256, 4) void cfconv_fused(
    const float* __restrict__ x,
    const float* __restrict__ dR,
    const float* __restrict__ dRe,
    const float* __restrict__ mask,
    const int*   __restrict__ nbr,
    const float* __restrict__ b1,
    const float* __restrict__ b2,
    const float* __restrict__ W1,
    const float* __restrict__ W2,
    const float* __restrict__ Wi,
    const float* __restrict__ Wo,
    const float* __restrict__ bf2o,
    unsigned short* __restrict__ wsb,
    unsigned short* __restrict__ yfeatb,
    unsigned short* __restrict__ dreb,
    unsigned int* bar,
    float* __restrict__ out)
{
    __shared__ __align__(16) unsigned short s_H[NK * HP];    // 13056 B
    __shared__ __align__(16) unsigned short s_yf[NK * YFP];  // 13056 B
    __shared__ float s_cm[NK];                               // 192 B

    const int tid  = threadIdx.x;
    const int bid  = blockIdx.x;
    const int nblk = gridDim.x;
    const unsigned int NB = (unsigned int)nblk;

    const int w = tid >> 6;
    const int lane = tid & 63;
    const int r = lane & 15;
    const int q = lane >> 4;
    const int nt0 = w * 2;
    const int kb = tid >> 4;
    const int sp = tid & 15;

    const unsigned short* W1T = wsb;
    const unsigned short* W2T = wsb + 4096;
    const unsigned short* WiT = wsb + 20480;
    const unsigned short* WoT = wsb + 36864;

    // ---------------- phase 0: weight transposes + dreb transform ----------------
    {
        int i = bid * 256 + tid;
        if (i < 4096) {                       // W1T[f][g], g padded to 32
            int f = i >> 5, g = i & 31;
            wsb[i] = (g < 25) ? f2bs(W1[g * NF + f]) : (unsigned short)0;
        } else if (i < 20480) {               // W2T[h][j]
            int j = i - 4096; int h = j >> 7, k = j & 127;
            wsb[i] = f2bs(W2[k * NF + h]);
        } else if (i < 36864) {               // WiT[f][i]
            int j = i - 20480; int f = j >> 7, k = j & 127;
            wsb[i] = f2bs(Wi[k * NF + f]);
        } else if (i < 53248) {               // WoT[o][f]
            int j = i - 36864; int f = j >> 7, k = j & 127;
            wsb[i] = f2bs(Wo[k * NF + f]);
        }

        // dreb transform (r8-proven body), grid-stride over all blocks
        const float4* src = (const float4*)dRe;
        for (int j = bid * 256 + tid; j < 3000000; j += nblk * 256) {
            float4 v = src[j];
            int n  = j / 300;
            int rm = j - n * 300;
            int i2 = rm * 4;
            int k  = i2 / 25;
            int g  = i2 - k * 25;
            unsigned short* dst = dreb + (size_t)n * 1536;
            float vv[4] = {v.x, v.y, v.z, v.w};
            #pragma unroll
            for (int e = 0; e < 4; ++e) {
                dst[k * 32 + g] = f2bs(vv[e]);
                if (++g == 25) {
                    #pragma unroll
                    for (int p = 25; p < 32; ++p) dst[k * 32 + p] = 0;
                    g = 0; ++k;
                }
            }
        }
    }
    gridbar(bar + 0, NB);

    // ---------------- phase 1: in2f (r1-proven global-WiT MFMA) ----------------
    for (int tile = bid; tile < 157; tile += nblk) {
        const int m0 = tile * 64 + w * 16;
        const int row = m0 + r;
        const bool rv = (row < NA);

        f32x4 acc[8];
        #pragma unroll
        for (int nt = 0; nt < 8; ++nt) { acc[nt][0]=0.f; acc[nt][1]=0.f; acc[nt][2]=0.f; acc[nt][3]=0.f; }

        #pragma unroll
        for (int ks = 0; ks < 4; ++ks) {
            bf16x8 a;
            if (rv) {
                const float4* xp = (const float4*)(x + (size_t)row * NF + ks * 32 + q * 8);
                float4 v0 = xp[0], v1 = xp[1];
                a[0]=(__bf16)v0.x; a[1]=(__bf16)v0.y; a[2]=(__bf16)v0.z; a[3]=(__bf16)v0.w;
                a[4]=(__bf16)v1.x; a[5]=(__bf16)v1.y; a[6]=(__bf16)v1.z; a[7]=(__bf16)v1.w;
            } else {
                #pragma unroll
                for (int j = 0; j < 8; ++j) a[j] = (__bf16)0.0f;
            }
            #pragma unroll
            for (int nt = 0; nt < 8; ++nt) {
                bf16x8 b = *(const bf16x8*)(WiT + (nt * 16 + r) * NF + ks * 32 + q * 8);
                acc[nt] = __builtin_amdgcn_mfma_f32_16x16x32_bf16(a, b, acc[nt], 0, 0, 0);
            }
        }
        #pragma unroll
        for (int nt = 0; nt < 8; ++nt) {
            #pragma unroll
            for (int reg = 0; reg < 4; ++reg) {
                int orow = m0 + q * 4 + reg;
                if (orow < NA)
                    yfeatb[(size_t)orow * NF + nt * 16 + r] = f2bs(acc[nt][reg]);
            }
        }
    }
    gridbar(bar + 1, NB);

    // ---------------- phase 2: pipelined cfconv (r11 verbatim, stride nblk) ----------------
    {
        const bf16x8 bfr0 = *(const bf16x8*)(W1T + ((nt0    ) * 16 + r) * 32 + q * 8);
        const bf16x8 bfr1 = *(const bf16x8*)(W1T + ((nt0 + 1) * 16 + r) * 32 + q * 8);
        bf16x8 bw[2][4];
        #pragma unroll
        for (int t = 0; t < 2; ++t)
            #pragma unroll
            for (int ks = 0; ks < 4; ++ks)
                bw[t][ks] = *(const bf16x8*)(W2T + ((nt0 + t) * 16 + r) * NF + ks * 32 + q * 8);
        const float bias1a = b1[nt0 * 16 + r];
        const float bias1b = b1[nt0 * 16 + 16 + r];
        const float bias2a = b2[nt0 * 16 + r];
        const float bias2b = b2[nt0 * 16 + 16 + r];

        bf16x8 g0, g1, g2;
        bf16x8 a0, a1, a2;
        float dv = 10.0f, mv = 0.0f;
        unsigned short hsv[24];

        auto prefetch = [&](int nn) {
            const int nb0 = nbr[nn * NK + kb] * NF;
            const int nb1 = nbr[nn * NK + kb + 16] * NF;
            const int nb2 = nbr[nn * NK + kb + 32] * NF;
            g0 = *(const bf16x8*)(yfeatb + nb0 + sp * 8);
            g1 = *(const bf16x8*)(yfeatb + nb1 + sp * 8);
            g2 = *(const bf16x8*)(yfeatb + nb2 + sp * 8);
            const unsigned short* dn = dreb + (size_t)nn * 1536;
            a0 = *(const bf16x8*)(dn + (     r) * 32 + q * 8);
            a1 = *(const bf16x8*)(dn + (16 + r) * 32 + q * 8);
            a2 = *(const bf16x8*)(dn + (32 + r) * 32 + q * 8);
            if (tid < NK) {
                dv = dR[nn * NK + tid];
                mv = mask[nn * NK + tid];
            }
        };

        auto stage1 = [&]() {
            #pragma unroll
            for (int mt = 0; mt < 3; ++mt) {
                bf16x8 av8 = (mt == 0) ? a0 : (mt == 1) ? a1 : a2;
                f32x4 zf; zf[0]=0.f; zf[1]=0.f; zf[2]=0.f; zf[3]=0.f;
                f32x4 h0v = __builtin_amdgcn_mfma_f32_16x16x32_bf16(av8, bfr0, zf, 0, 0, 0);
                f32x4 h1v = __builtin_amdgcn_mfma_f32_16x16x32_bf16(av8, bfr1, zf, 0, 0, 0);
                #pragma unroll
                for (int reg = 0; reg < 4; ++reg) {
                    hsv[mt * 8 + reg]     = f2bs(sspf(h0v[reg] + bias1a));
                    hsv[mt * 8 + 4 + reg] = f2bs(sspf(h1v[reg] + bias1b));
                }
            }
        };

        auto ldswrite = [&]() {
            #pragma unroll
            for (int mt = 0; mt < 3; ++mt) {
                #pragma unroll
                for (int reg = 0; reg < 4; ++reg) {
                    int k = mt * 16 + q * 4 + reg;
                    s_H[k * HP + nt0 * 16 + r]      = hsv[mt * 8 + reg];
                    s_H[k * HP + nt0 * 16 + 16 + r] = hsv[mt * 8 + 4 + reg];
                }
            }
            *(bf16x8*)(&s_yf[(kb     ) * YFP + sp * 8]) = g0;
            *(bf16x8*)(&s_yf[(kb + 16) * YFP + sp * 8]) = g1;
            *(bf16x8*)(&s_yf[(kb + 32) * YFP + sp * 8]) = g2;
            if (tid < NK)
                s_cm[tid] = (dv <= 5.0f) ? mv : 0.0f;
        };

        int n = bid;
        prefetch(n);
        stage1();
        ldswrite();
        __syncthreads();

        while (true) {
            const int n_next = n + nblk;
            const bool more = (n_next < NA);

            if (more) prefetch(n_next);

            f32x4 acc[3][2];
            #pragma unroll
            for (int mt = 0; mt < 3; ++mt)
                #pragma unroll
                for (int t = 0; t < 2; ++t) { acc[mt][t][0]=0.f; acc[mt][t][1]=0.f; acc[mt][t][2]=0.f; acc[mt][t][3]=0.f; }

            #pragma unroll
            for (int ks = 0; ks < 4; ++ks) {
                #pragma unroll
                for (int mt = 0; mt < 3; ++mt) {
                    bf16x8 ah = *(const bf16x8*)(&s_H[(mt * 16 + r) * HP + ks * 32 + q * 8]);
                    acc[mt][0] = __builtin_amdgcn_mfma_f32_16x16x32_bf16(ah, bw[0][ks], acc[mt][0], 0, 0, 0);
                    acc[mt][1] = __builtin_amdgcn_mfma_f32_16x16x32_bf16(ah, bw[1][ks], acc[mt][1], 0, 0, 0);
                }
            }

            if (more) stage1();

            float part0 = 0.f, part1 = 0.f;
            const int h0 = nt0 * 16 + r;
            #pragma unroll
            for (int mt = 0; mt < 3; ++mt) {
                #pragma unroll
                for (int reg = 0; reg < 4; ++reg) {
                    int k = mt * 16 + q * 4 + reg;
                    float cmk = s_cm[k];
                    part0 += cmk * (acc[mt][0][reg] + bias2a) * bs2f(s_yf[k * YFP + h0]);
                    part1 += cmk * (acc[mt][1][reg] + bias2b) * bs2f(s_yf[k * YFP + h0 + 16]);
                }
            }
            part0 += __shfl_xor(part0, 16);
            part0 += __shfl_xor(part0, 32);
            part1 += __shfl_xor(part1, 16);
            part1 += __shfl_xor(part1, 32);
            if (q == 0) {
                out[(size_t)n * NF + h0]      = part0;
                out[(size_t)n * NF + h0 + 16] = part1;
            }

            if (!more) break;

            __syncthreads();
            ldswrite();
            __syncthreads();
            n = n_next;
        }
    }
    gridbar(bar + 2, NB);

    // ---------------- phase 3: f2out in-place (r1-proven) ----------------
    for (int tile = bid; tile < 157; tile += nblk) {
        const int m0 = tile * 64 + w * 16;
        const int row = m0 + r;
        const bool rv = (row < NA);

        f32x4 acc[8];
        #pragma unroll
        for (int nt = 0; nt < 8; ++nt) { acc[nt][0]=0.f; acc[nt][1]=0.f; acc[nt][2]=0.f; acc[nt][3]=0.f; }

        #pragma unroll
        for (int ks = 0; ks < 4; ++ks) {
            bf16x8 a;
            if (rv) {
                const float4* yp = (const float4*)(out + (size_t)row * NF + ks * 32 + q * 8);
                float4 v0 = yp[0], v1 = yp[1];
                a[0]=(__bf16)v0.x; a[1]=(__bf16)v0.y; a[2]=(__bf16)v0.z; a[3]=(__bf16)v0.w;
                a[4]=(__bf16)v1.x; a[5]=(__bf16)v1.y; a[6]=(__bf16)v1.z; a[7]=(__bf16)v1.w;
            } else {
                #pragma unroll
                for (int j = 0; j < 8; ++j) a[j] = (__bf16)0.0f;
            }
            #pragma unroll
            for (int nt = 0; nt < 8; ++nt) {
                bf16x8 b = *(const bf16x8*)(WoT + (nt * 16 + r) * NF + ks * 32 + q * 8);
                acc[nt] = __builtin_amdgcn_mfma_f32_16x16x32_bf16(a, b, acc[nt], 0, 0, 0);
            }
        }
        #pragma unroll
        for (int nt = 0; nt < 8; ++nt) {
            float bia = bf2o[nt * 16 + r];
            #pragma unroll
            for (int reg = 0; reg < 4; ++reg) {
                int orow = m0 + q * 4 + reg;
                if (orow < NA)
                    out[(size_t)orow * NF + nt * 16 + r] = sspf(acc[nt][reg] + bia);
            }
        }
    }
}

// ==================== fallback path: exact r11 3-kernel config ====================

__global__ __launch_bounds__(256) void in2f_prep_fb(
    const float* __restrict__ x,
    const float* __restrict__ Wi,
    const float* __restrict__ W1,
    const float* __restrict__ W2,
    const float* __restrict__ Wo,
    const float* __restrict__ dRe,
    unsigned short* __restrict__ wsb,
    unsigned short* __restrict__ yfeatb,
    unsigned short* __restrict__ dreb)
{
    const int tid = threadIdx.x;

    if (blockIdx.x >= 301) {
        const float4* src = (const float4*)dRe;
        for (int j = (blockIdx.x - 301) * 256 + tid; j < 3000000; j += 768 * 256) {
            float4 v = src[j];
            int n  = j / 300;
            int rm = j - n * 300;
            int i  = rm * 4;
            int k  = i / 25;
            int g  = i - k * 25;
            unsigned short* dst = dreb + (size_t)n * 1536;
            float vv[4] = {v.x, v.y, v.z, v.w};
            #pragma unroll
            for (int e = 0; e < 4; ++e) {
                dst[k * 32 + g] = f2bs(vv[e]);
                if (++g == 25) {
                    #pragma unroll
                    for (int p = 25; p < 32; ++p) dst[k * 32 + p] = 0;
                    g = 0; ++k;
                }
            }
        }
        return;
    }

    if (blockIdx.x >= 157) {
        int i = (blockIdx.x - 157) * 256 + tid;
        if (i < 4096) {
            int f = i >> 5, g = i & 31;
            wsb[i] = (g < 25) ? f2bs(W1[g * NF + f]) : (unsigned short)0;
        } else if (i < 20480) {
            int j = i - 4096; int h = j >> 7, k = j & 127;
            wsb[i] = f2bs(W2[k * NF + h]);
        } else {
            int j = i - 20480; int f = j >> 7, k = j & 127;
            wsb[i] = f2bs(Wo[k * NF + f]);
        }
        return;
    }

    __shared__ __align__(16) unsigned short s_wi[NF * 136];
    {
        const float4* wi4 = (const float4*)Wi;
        #pragma unroll
        for (int it = 0; it < 16; ++it) {
            int idx4 = it * 256 + tid;
            float4 v = wi4[idx4];
            int i = idx4 >> 5;
            int f = (idx4 & 31) * 4;
            s_wi[(f + 0) * 136 + i] = f2bs(v.x);
            s_wi[(f + 1) * 136 + i] = f2bs(v.y);
            s_wi[(f + 2) * 136 + i] = f2bs(v.z);
            s_wi[(f + 3) * 136 + i] = f2bs(v.w);
        }
    }
    __syncthreads();

    const int w = tid >> 6;
    const int lane = tid & 63;
    const int r = lane & 15;
    const int q = lane >> 4;
    const int m0 = blockIdx.x * 64 + w * 16;
    const int row = m0 + r;
    const bool rv = (row < NA);

    f32x4 acc[8];
    #pragma unroll
    for (int nt = 0; nt < 8; ++nt) { acc[nt][0]=0.f; acc[nt][1]=0.f; acc[nt][2]=0.f; acc[nt][3]=0.f; }

    #pragma unroll
    for (int ks = 0; ks < 4; ++ks) {
        bf16x8 a;
        if (rv) {
            const float4* xp = (const float4*)(x + (size_t)row * NF + ks * 32 + q * 8);
            float4 v0 = xp[0], v1 = xp[1];
            a[0]=(__bf16)v0.x; a[1]=(__bf16)v0.y; a[2]=(__bf16)v0.z; a[3]=(__bf16)v0.w;
            a[4]=(__bf16)v1.x; a[5]=(__bf16)v1.y; a[6]=(__bf16)v1.z; a[7]=(__bf16)v1.w;
        } else {
            #pragma unroll
            for (int j = 0; j < 8; ++j) a[j] = (__bf16)0.0f;
        }
        #pragma unroll
        for (int nt = 0; nt < 8; ++nt) {
            bf16x8 b = *(const bf16x8*)(&s_wi[(nt * 16 + r) * 136 + ks * 32 + q * 8]);
            acc[nt] = __builtin_amdgcn_mfma_f32_16x16x32_bf16(a, b, acc[nt], 0, 0, 0);
        }
    }
    #pragma unroll
    for (int nt = 0; nt < 8; ++nt) {
        #pragma unroll
        for (int reg = 0; reg < 4; ++reg) {
            int orow = m0 + q * 4 + reg;
            if (orow < NA)
                yfeatb[(size_t)orow * NF + nt * 16 + r] = f2bs(acc[nt][reg]);
        }
    }
}

__global__ __launch_bounds__(256, 4) void cfconv_pp_fb(
    const float* __restrict__ dR,
    const float* __restrict__ mask,
    const int*   __restrict__ nbr,
    const float* __restrict__ b1,
    const float* __restrict__ b2,
    const unsigned short* __restrict__ W1T,
    const unsigned short* __restrict__ W2T,
    const unsigned short* __restrict__ dreb,
    const unsigned short* __restrict__ yfeatb,
    float* __restrict__ yout)
{
    __shared__ __align__(16) unsigned short s_H[NK * HP];
    __shared__ __align__(16) unsigned short s_yf[NK * YFP];
    __shared__ float s_cm[NK];

    const int tid = threadIdx.x;
    const int w = tid >> 6;
    const int lane = tid & 63;
    const int r = lane & 15;
    const int q = lane >> 4;
    const int nt0 = w * 2;
    const int kb = tid >> 4;
    const int sp = tid & 15;

    const bf16x8 bfr0 = *(const bf16x8*)(W1T + ((nt0    ) * 16 + r) * 32 + q * 8);
    const bf16x8 bfr1 = *(const bf16x8*)(W1T + ((nt0 + 1) * 16 + r) * 32 + q * 8);
    bf16x8 bw[2][4];
    #pragma unroll
    for (int t = 0; t < 2; ++t)
        #pragma unroll
        for (int ks = 0; ks < 4; ++ks)
            bw[t][ks] = *(const bf16x8*)(W2T + ((nt0 + t) * 16 + r) * NF + ks * 32 + q * 8);
    const float bias1a = b1[nt0 * 16 + r];
    const float bias1b = b1[nt0 * 16 + 16 + r];
    const float bias2a = b2[nt0 * 16 + r];
    const float bias2b = b2[nt0 * 16 + 16 + r];

    bf16x8 g0, g1, g2, a0, a1, a2;
    float dv = 10.0f, mv = 0.0f;
    unsigned short hsv[24];

    auto prefetch = [&](int nn) {
        const int nb0 = nbr[nn * NK + kb] * NF;
        const int nb1 = nbr[nn * NK + kb + 16] * NF;
        const int nb2 = nbr[nn * NK + kb + 32] * NF;
        g0 = *(const bf16x8*)(yfeatb + nb0 + sp * 8);
        g1 = *(const bf16x8*)(yfeatb + nb1 + sp * 8);
        g2 = *(const bf16x8*)(yfeatb + nb2 + sp * 8);
        const unsigned short* dn = dreb + (size_t)nn * 1536;
        a0 = *(const bf16x8*)(dn + (     r) * 32 + q * 8);
        a1 = *(const bf16x8*)(dn + (16 + r) * 32 + q * 8);
        a2 = *(const bf16x8*)(dn + (32 + r) * 32 + q * 8);
        if (tid < NK) { dv = dR[nn * NK + tid]; mv = mask[nn * NK + tid]; }
    };
    auto stage1 = [&]() {
        #pragma unroll
        for (int mt = 0; mt < 3; ++mt) {
            bf16x8 av8 = (mt == 0) ? a0 : (mt == 1) ? a1 : a2;
            f32x4 zf; zf[0]=0.f; zf[1]=0.f; zf[2]=0.f; zf[3]=0.f;
            f32x4 h0v = __builtin_amdgcn_mfma_f32_16x16x32_bf16(av8, bfr0, zf, 0, 0, 0);
            f32x4 h1v = __builtin_amdgcn_mfma_f32_16x16x32_bf16(av8, bfr1, zf, 0, 0, 0);
            #pragma unroll
            for (int reg = 0; reg < 4; ++reg) {
                hsv[mt * 8 + reg]     = f2bs(sspf(h0v[reg] + bias1a));
                hsv[mt * 8 + 4 + reg] = f2bs(sspf(h1v[reg] + bias1b));
            }
        }
    };
    auto ldswrite = [&]() {
        #pragma unroll
        for (int mt = 0; mt < 3; ++mt)
            #pragma unroll
            for (int reg = 0; reg < 4; ++reg) {
                int k = mt * 16 + q * 4 + reg;
                s_H[k * HP + nt0 * 16 + r]      = hsv[mt * 8 + reg];
                s_H[k * HP + nt0 * 16 + 16 + r] = hsv[mt * 8 + 4 + reg];
            }
        *(bf16x8*)(&s_yf[(kb     ) * YFP + sp * 8]) = g0;
        *(bf16x8*)(&s_yf[(kb + 16) * YFP + sp * 8]) = g1;
        *(bf16x8*)(&s_yf[(kb + 32) * YFP + sp * 8]) = g2;
        if (tid < NK) s_cm[tid] = (dv <= 5.0f) ? mv : 0.0f;
    };

    int n = blockIdx.x;
    prefetch(n); stage1(); ldswrite();
    __syncthreads();

    while (true) {
        const int n_next = n + 1024;
        const bool more = (n_next < NA);
        if (more) prefetch(n_next);

        f32x4 acc[3][2];
        #pragma unroll
        for (int mt = 0; mt < 3; ++mt)
            #pragma unroll
            for (int t = 0; t < 2; ++t) { acc[mt][t][0]=0.f; acc[mt][t][1]=0.f; acc[mt][t][2]=0.f; acc[mt][t][3]=0.f; }

        #pragma unroll
        for (int ks = 0; ks < 4; ++ks)
            #pragma unroll
            for (int mt = 0; mt < 3; ++mt) {
                bf16x8 ah = *(const bf16x8*)(&s_H[(mt * 16 + r) * HP + ks * 32 + q * 8]);
                acc[mt][0] = __builtin_amdgcn_mfma_f32_16x16x32_bf16(ah, bw[0][ks], acc[mt][0], 0, 0, 0);
                acc[mt][1] = __builtin_amdgcn_mfma_f32_16x16x32_bf16(ah, bw[1][ks], acc[mt][1], 0, 0, 0);
            }

        if (more) stage1();

        float part0 = 0.f, part1 = 0.f;
        const int h0 = nt0 * 16 + r;
        #pragma unroll
        for (int mt = 0; mt < 3; ++mt)
            #pragma unroll
            for (int reg = 0; reg < 4; ++reg) {
                int k = mt * 16 + q * 4 + reg;
                float cmk = s_cm[k];
                part0 += cmk * (acc[mt][0][reg] + bias2a) * bs2f(s_yf[k * YFP + h0]);
                part1 += cmk * (acc[mt][1][reg] + bias2b) * bs2f(s_yf[k * YFP + h0 + 16]);
            }
        part0 += __shfl_xor(part0, 16);
        part0 += __shfl_xor(part0, 32);
        part1 += __shfl_xor(part1, 16);
        part1 += __shfl_xor(part1, 32);
        if (q == 0) {
            yout[(size_t)n * NF + h0]      = part0;
            yout[(size_t)n * NF + h0 + 16] = part1;
        }

        if (!more) break;
        __syncthreads();
        ldswrite();
        __syncthreads();
        n = n_next;
    }
}

__global__ __launch_bounds__(256) void f2out_mfma_fb(
    const unsigned short* __restrict__ WoT,
    const float* __restrict__ bo,
    float* io)
{
    const int tid = threadIdx.x;
    const int w = tid >> 6;
    const int lane = tid & 63;
    const int r = lane & 15;
    const int q = lane >> 4;
    const int m0 = blockIdx.x * 64 + w * 16;
    const int row = m0 + r;
    const bool rv = (row < NA);

    f32x4 acc[8];
    #pragma unroll
    for (int nt = 0; nt < 8; ++nt) { acc[nt][0]=0.f; acc[nt][1]=0.f; acc[nt][2]=0.f; acc[nt][3]=0.f; }

    #pragma unroll
    for (int ks = 0; ks < 4; ++ks) {
        bf16x8 a;
        if (rv) {
            const float4* yp = (const float4*)(io + (size_t)row * NF + ks * 32 + q * 8);
            float4 v0 = yp[0], v1 = yp[1];
            a[0]=(__bf16)v0.x; a[1]=(__bf16)v0.y; a[2]=(__bf16)v0.z; a[3]=(__bf16)v0.w;
            a[4]=(__bf16)v1.x; a[5]=(__bf16)v1.y; a[6]=(__bf16)v1.z; a[7]=(__bf16)v1.w;
        } else {
            #pragma unroll
            for (int j = 0; j < 8; ++j) a[j] = (__bf16)0.0f;
        }
        #pragma unroll
        for (int nt = 0; nt < 8; ++nt) {
            bf16x8 b = *(const bf16x8*)(WoT + (nt * 16 + r) * NF + ks * 32 + q * 8);
            acc[nt] = __builtin_amdgcn_mfma_f32_16x16x32_bf16(a, b, acc[nt], 0, 0, 0);
        }
    }
    #pragma unroll
    for (int nt = 0; nt < 8; ++nt) {
        float bia = bo[nt * 16 + r];
        #pragma unroll
        for (int reg = 0; reg < 4; ++reg) {
            int orow = m0 + q * 4 + reg;
            if (orow < NA)
                io[(size_t)orow * NF + nt * 16 + r] = sspf(acc[nt][reg] + bia);
        }
    }
}

extern "C" void kernel_launch(void* const* d_in, const int* in_sizes, int n_in,
                              void* d_out, int out_size, void* d_ws, size_t ws_size,
                              hipStream_t stream)
{
    const float* x    = (const float*)d_in[0];
    const float* dR   = (const float*)d_in[1];
    const float* dRe  = (const float*)d_in[2];
    const float* mask = (const float*)d_in[3];
    const int*   nbr  = (const int*)d_in[4];
    const float* W1   = (const float*)d_in[5];
    const float* b1   = (const float*)d_in[6];
    const float* W2   = (const float*)d_in[7];
    const float* b2   = (const float*)d_in[8];
    const float* Wi2f = (const float*)d_in[9];
    const float* Wf2o = (const float*)d_in[10];
    const float* bf2o = (const float*)d_in[11];
    float* out = (float*)d_out;

    unsigned short* wsb = (unsigned short*)d_ws;

    // ---- fused path: needs 33386752 B (layout + 128 B barrier counters) ----
    bool fused_ok = ws_size >= 33386752ULL;
    int occ = 0;
    if (fused_ok) {
        if (hipOccupancyMaxActiveBlocksPerMultiprocessor(&occ, cfconv_fused, 256, 0) != hipSuccess)
            occ = 0;
        if (occ < 1) fused_ok = false;
    }

    if (fused_ok) {
        unsigned short* yfb  = wsb + 53248;     // 1,280,000 elems
        unsigned short* dreb = wsb + 1333248;   // 15,360,000 elems
        unsigned int*   bar  = (unsigned int*)(wsb + 16693248);
        int bpc  = occ > 6 ? 6 : occ;           // LDS cap is 6 blocks/CU
        int grid = bpc * 256;
        if (grid > 1536) grid = 1536;
        hipMemsetAsync(bar, 0, 128, stream);
        cfconv_fused<<<grid, 256, 0, stream>>>(x, dR, dRe, mask, nbr, b1, b2,
                                               W1, W2, Wi2f, Wf2o, bf2o,
                                               wsb, yfb, dreb, bar, out);
    } else {
        // ---- fallback: exact r11 3-kernel config (ws >= 33353728 proven) ----
        unsigned short* W1T    = wsb;
        unsigned short* W2T    = wsb + 4096;
        unsigned short* WoT    = wsb + 20480;
        unsigned short* yfeatb = wsb + 36864;
        unsigned short* dreb   = wsb + 1316864;
        in2f_prep_fb<<<1069, 256, 0, stream>>>(x, Wi2f, W1, W2, Wf2o, dRe,
                                               wsb, yfeatb, dreb);
        cfconv_pp_fb<<<1024, 256, 0, stream>>>(dR, mask, nbr, b1, b2,
                                               W1T, W2T, dreb, yfeatb, out);
        f2out_mfma_fb<<<157, 256, 0, stream>>>(WoT, bf2o, out);
    }
}

// Round 11
// 298.504 us; speedup vs baseline: 1.9129x; 1.4600x over previous
//
#include <hip/hip_runtime.h>
#include <hip/hip_bf16.h>

// SchNet CFConv, MI355X gfx950 — round 14: best-of-ledger recombination.
// Fusion abandoned (r12/r13: grid-barrier path 552-899us, mechanism unmodeled).
// Take r6's 4-kernel scaffolding (cheapest "rest" = 89.5us: prep_weights /
// in2f global-WiT / cfconv / f2out) and swap in r11's PIPELINED persistent
// cfconv (73us proven) with dreb REMOVED: prefetch reads dRe directly via the
// r4-proven memcpy path (floats staged in 24 VGPRs, converted in stage1 which
// overlaps stage2's MFMAs -> latency and instruction cost mostly hidden).
// No dreb => no +30us prep bloat, ws back to 2.63 MB.
//
// d_ws layout (unsigned short elements):
//   [0      .. 4096  )  W1T  bf16 [128 f][32 gpad]   (g>=25 zero)
//   [4096   .. 20480 )  W2T  bf16 [128 h][128 j]
//   [20480  .. 36864 )  WiT  bf16 [128 f][128 i]
//   [36864  .. 53248 )  WoT  bf16 [128 o][128 f]
//   [53248  .. +1.28M)  yfeatb bf16 [10000][128]

#define NA 10000
#define NK 48
#define NF 128
#define HP  136   // s_H  row pad (bf16): 272 B rows -> 2-way (free)
#define YFP 136   // s_yf row pad (bf16)
#define GRID_CF 1024

typedef __bf16 bf16x8 __attribute__((ext_vector_type(8)));
typedef float  f32x4  __attribute__((ext_vector_type(4)));

__device__ __forceinline__ unsigned short f2bs(float x) {
    return __builtin_bit_cast(unsigned short, (__bf16)x);
}
__device__ __forceinline__ float bs2f(unsigned short u) {
    return (float)__builtin_bit_cast(__bf16, u);
}
__device__ __forceinline__ float sspf(float v) {
    return fmaxf(v, 0.0f) + __logf(1.0f + __expf(-fabsf(v))) - 0.69314718056f;
}

// ---- kernel 1: transpose-convert weights to bf16 in d_ws (r6-proven) ----
__global__ __launch_bounds__(256) void prep_weights(
    const float* __restrict__ W1,
    const float* __restrict__ W2,
    const float* __restrict__ Wi,
    const float* __restrict__ Wo,
    unsigned short* __restrict__ wsb)
{
    int i = blockIdx.x * 256 + threadIdx.x;
    if (i < 4096) {                       // W1T[f][g], g padded to 32
        int f = i >> 5, g = i & 31;
        wsb[i] = (g < 25) ? f2bs(W1[g * NF + f]) : (unsigned short)0;
    } else if (i < 20480) {               // W2T[h][j]
        int j = i - 4096; int h = j >> 7, k = j & 127;
        wsb[i] = f2bs(W2[k * NF + h]);
    } else if (i < 36864) {               // WiT[f][i]
        int j = i - 20480; int f = j >> 7, k = j & 127;
        wsb[i] = f2bs(Wi[k * NF + f]);
    } else if (i < 53248) {               // WoT[o][f]
        int j = i - 36864; int f = j >> 7, k = j & 127;
        wsb[i] = f2bs(Wo[k * NF + f]);
    }
}

// ---- kernel 2: in2f yfeatb = bf16(x @ W_in2f), global-WiT MFMA (r6-proven) ----
__global__ __launch_bounds__(256) void in2f_mfma(
    const float* __restrict__ x,
    const unsigned short* __restrict__ WiT,
    unsigned short* __restrict__ yfeatb)
{
    const int tid = threadIdx.x;
    const int w = tid >> 6;
    const int lane = tid & 63;
    const int r = lane & 15;
    const int q = lane >> 4;
    const int m0 = blockIdx.x * 64 + w * 16;
    const int row = m0 + r;
    const bool rv = (row < NA);

    f32x4 acc[8];
    #pragma unroll
    for (int nt = 0; nt < 8; ++nt) { acc[nt][0]=0.f; acc[nt][1]=0.f; acc[nt][2]=0.f; acc[nt][3]=0.f; }

    #pragma unroll
    for (int ks = 0; ks < 4; ++ks) {
        bf16x8 a;
        if (rv) {
            const float4* xp = (const float4*)(x + (size_t)row * NF + ks * 32 + q * 8);
            float4 v0 = xp[0], v1 = xp[1];
            a[0]=(__bf16)v0.x; a[1]=(__bf16)v0.y; a[2]=(__bf16)v0.z; a[3]=(__bf16)v0.w;
            a[4]=(__bf16)v1.x; a[5]=(__bf16)v1.y; a[6]=(__bf16)v1.z; a[7]=(__bf16)v1.w;
        } else {
            #pragma unroll
            for (int j = 0; j < 8; ++j) a[j] = (__bf16)0.0f;
        }
        #pragma unroll
        for (int nt = 0; nt < 8; ++nt) {
            bf16x8 b = *(const bf16x8*)(WiT + (nt * 16 + r) * NF + ks * 32 + q * 8);
            acc[nt] = __builtin_amdgcn_mfma_f32_16x16x32_bf16(a, b, acc[nt], 0, 0, 0);
        }
    }
    #pragma unroll
    for (int nt = 0; nt < 8; ++nt) {
        #pragma unroll
        for (int reg = 0; reg < 4; ++reg) {
            int orow = m0 + q * 4 + reg;
            if (orow < NA)
                yfeatb[(size_t)orow * NF + nt * 16 + r] = f2bs(acc[nt][reg]);
        }
    }
}

// ---- kernel 3: pipelined persistent cfconv, DIRECT dRe (no dreb) ----
__global__ __launch_bounds__(256, 4) void cfconv_ppd(
    const float* __restrict__ dR,
    const float* __restrict__ dRe,
    const float* __restrict__ mask,
    const int*   __restrict__ nbr,
    const float* __restrict__ b1,
    const float* __restrict__ b2,
    const unsigned short* __restrict__ W1T,
    const unsigned short* __restrict__ W2T,
    const unsigned short* __restrict__ yfeatb,
    float* __restrict__ yout)
{
    __shared__ __align__(16) unsigned short s_H[NK * HP];    // 13056 B
    __shared__ __align__(16) unsigned short s_yf[NK * YFP];  // 13056 B
    __shared__ float s_cm[NK];                               // 192 B

    const int tid = threadIdx.x;
    const int w = tid >> 6;
    const int lane = tid & 63;
    const int r = lane & 15;
    const int q = lane >> 4;
    const int nt0 = w * 2;
    const int kb = tid >> 4;
    const int sp = tid & 15;

    // ---- hoisted weights/biases (amortized over ~10 atoms) ----
    const bf16x8 bfr0 = *(const bf16x8*)(W1T + ((nt0    ) * 16 + r) * 32 + q * 8);
    const bf16x8 bfr1 = *(const bf16x8*)(W1T + ((nt0 + 1) * 16 + r) * 32 + q * 8);
    bf16x8 bw[2][4];
    #pragma unroll
    for (int t = 0; t < 2; ++t)
        #pragma unroll
        for (int ks = 0; ks < 4; ++ks)
            bw[t][ks] = *(const bf16x8*)(W2T + ((nt0 + t) * 16 + r) * NF + ks * 32 + q * 8);
    const float bias1a = b1[nt0 * 16 + r];
    const float bias1b = b1[nt0 * 16 + 16 + r];
    const float bias2a = b2[nt0 * 16 + r];
    const float bias2b = b2[nt0 * 16 + 16 + r];

    // ---- pipeline registers ----
    bf16x8 g0, g1, g2;          // gathered neighbor rows (next atom)
    float  fv[3][8];            // raw dRe floats (next atom), 24 VGPR
    float dv = 10.0f, mv = 0.0f;
    unsigned short hsv[24];     // stage1 output bf16 bits, statically indexed

    // prefetch: issue ALL of next atom's global loads (latency hides under
    // current atom's stage2/agg); floats converted later in stage1.
    auto prefetch = [&](int nn) {
        const int nb0 = nbr[nn * NK + kb] * NF;
        const int nb1 = nbr[nn * NK + kb + 16] * NF;
        const int nb2 = nbr[nn * NK + kb + 32] * NF;
        g0 = *(const bf16x8*)(yfeatb + nb0 + sp * 8);
        g1 = *(const bf16x8*)(yfeatb + nb1 + sp * 8);
        g2 = *(const bf16x8*)(yfeatb + nb2 + sp * 8);
        const float* dre_n = dRe + (size_t)nn * (NK * 25);
        if (q < 3) {
            #pragma unroll
            for (int mt = 0; mt < 3; ++mt)
                __builtin_memcpy(fv[mt], dre_n + (mt * 16 + r) * 25 + q * 8, 32);
        } else {
            #pragma unroll
            for (int mt = 0; mt < 3; ++mt)
                fv[mt][0] = dre_n[(mt * 16 + r) * 25 + 24];
        }
        if (tid < NK) {
            dv = dR[nn * NK + tid];
            mv = mask[nn * NK + tid];
        }
    };

    // stage1: convert floats -> bf16 A-frags, MFMA vs W1, ssp -> hsv (regs)
    auto stage1 = [&]() {
        #pragma unroll
        for (int mt = 0; mt < 3; ++mt) {
            bf16x8 av8;
            if (q < 3) {
                #pragma unroll
                for (int j = 0; j < 8; ++j) av8[j] = (__bf16)fv[mt][j];
            } else {
                av8[0] = (__bf16)fv[mt][0];
                #pragma unroll
                for (int j = 1; j < 8; ++j) av8[j] = (__bf16)0.0f;
            }
            f32x4 zf; zf[0]=0.f; zf[1]=0.f; zf[2]=0.f; zf[3]=0.f;
            f32x4 h0v = __builtin_amdgcn_mfma_f32_16x16x32_bf16(av8, bfr0, zf, 0, 0, 0);
            f32x4 h1v = __builtin_amdgcn_mfma_f32_16x16x32_bf16(av8, bfr1, zf, 0, 0, 0);
            #pragma unroll
            for (int reg = 0; reg < 4; ++reg) {
                hsv[mt * 8 + reg]     = f2bs(sspf(h0v[reg] + bias1a));
                hsv[mt * 8 + 4 + reg] = f2bs(sspf(h1v[reg] + bias1b));
            }
        }
    };

    auto ldswrite = [&]() {
        #pragma unroll
        for (int mt = 0; mt < 3; ++mt) {
            #pragma unroll
            for (int reg = 0; reg < 4; ++reg) {
                int k = mt * 16 + q * 4 + reg;
                s_H[k * HP + nt0 * 16 + r]      = hsv[mt * 8 + reg];
                s_H[k * HP + nt0 * 16 + 16 + r] = hsv[mt * 8 + 4 + reg];
            }
        }
        *(bf16x8*)(&s_yf[(kb     ) * YFP + sp * 8]) = g0;
        *(bf16x8*)(&s_yf[(kb + 16) * YFP + sp * 8]) = g1;
        *(bf16x8*)(&s_yf[(kb + 32) * YFP + sp * 8]) = g2;
        if (tid < NK)
            s_cm[tid] = (dv <= 5.0f) ? mv : 0.0f;
    };

    // ---- prologue: fill pipeline for first atom ----
    int n = blockIdx.x;
    prefetch(n);
    stage1();
    ldswrite();
    __syncthreads();   // barrier A(0)

    while (true) {
        const int n_next = n + GRID_CF;
        const bool more = (n_next < NA);

        if (more) prefetch(n_next);   // issue next atom's globals early

        // ---- stage 2 for atom n: A2 = H @ W2 ----
        f32x4 acc[3][2];
        #pragma unroll
        for (int mt = 0; mt < 3; ++mt)
            #pragma unroll
            for (int t = 0; t < 2; ++t) { acc[mt][t][0]=0.f; acc[mt][t][1]=0.f; acc[mt][t][2]=0.f; acc[mt][t][3]=0.f; }

        #pragma unroll
        for (int ks = 0; ks < 4; ++ks) {
            #pragma unroll
            for (int mt = 0; mt < 3; ++mt) {
                bf16x8 ah = *(const bf16x8*)(&s_H[(mt * 16 + r) * HP + ks * 32 + q * 8]);
                acc[mt][0] = __builtin_amdgcn_mfma_f32_16x16x32_bf16(ah, bw[0][ks], acc[mt][0], 0, 0, 0);
                acc[mt][1] = __builtin_amdgcn_mfma_f32_16x16x32_bf16(ah, bw[1][ks], acc[mt][1], 0, 0, 0);
            }
        }

        if (more) stage1();           // next atom's stage1 (reg-only, overlaps)

        // ---- aggregation for atom n ----
        float part0 = 0.f, part1 = 0.f;
        const int h0 = nt0 * 16 + r;
        #pragma unroll
        for (int mt = 0; mt < 3; ++mt) {
            #pragma unroll
            for (int reg = 0; reg < 4; ++reg) {
                int k = mt * 16 + q * 4 + reg;
                float cmk = s_cm[k];
                part0 += cmk * (acc[mt][0][reg] + bias2a) * bs2f(s_yf[k * YFP + h0]);
                part1 += cmk * (acc[mt][1][reg] + bias2b) * bs2f(s_yf[k * YFP + h0 + 16]);
            }
        }
        part0 += __shfl_xor(part0, 16);
        part0 += __shfl_xor(part0, 32);
        part1 += __shfl_xor(part1, 16);
        part1 += __shfl_xor(part1, 32);
        if (q == 0) {
            yout[(size_t)n * NF + h0]      = part0;
            yout[(size_t)n * NF + h0 + 16] = part1;
        }

        if (!more) break;

        __syncthreads();   // barrier B: all reads of s_H/s_yf/s_cm done
        ldswrite();        // exchange window: dump next atom to LDS
        __syncthreads();   // barrier A: next atom's LDS ready
        n = n_next;
    }
}

// ---- kernel 4: f2out = ssp(y @ Wf2o + b), MFMA, IN PLACE on out (r6-proven) ----
__global__ __launch_bounds__(256) void f2out_mfma(
    const unsigned short* __restrict__ WoT,
    const float* __restrict__ bo,
    float* io)
{
    const int tid = threadIdx.x;
    const int w = tid >> 6;
    const int lane = tid & 63;
    const int r = lane & 15;
    const int q = lane >> 4;
    const int m0 = blockIdx.x * 64 + w * 16;
    const int row = m0 + r;
    const bool rv = (row < NA);

    f32x4 acc[8];
    #pragma unroll
    for (int nt = 0; nt < 8; ++nt) { acc[nt][0]=0.f; acc[nt][1]=0.f; acc[nt][2]=0.f; acc[nt][3]=0.f; }

    #pragma unroll
    for (int ks = 0; ks < 4; ++ks) {
        bf16x8 a;
        if (rv) {
            const float4* yp = (const float4*)(io + (size_t)row * NF + ks * 32 + q * 8);
            float4 v0 = yp[0], v1 = yp[1];
            a[0]=(__bf16)v0.x; a[1]=(__bf16)v0.y; a[2]=(__bf16)v0.z; a[3]=(__bf16)v0.w;
            a[4]=(__bf16)v1.x; a[5]=(__bf16)v1.y; a[6]=(__bf16)v1.z; a[7]=(__bf16)v1.w;
        } else {
            #pragma unroll
            for (int j = 0; j < 8; ++j) a[j] = (__bf16)0.0f;
        }
        #pragma unroll
        for (int nt = 0; nt < 8; ++nt) {
            bf16x8 b = *(const bf16x8*)(WoT + (nt * 16 + r) * NF + ks * 32 + q * 8);
            acc[nt] = __builtin_amdgcn_mfma_f32_16x16x32_bf16(a, b, acc[nt], 0, 0, 0);
        }
    }
    #pragma unroll
    for (int nt = 0; nt < 8; ++nt) {
        float bia = bo[nt * 16 + r];
        #pragma unroll
        for (int reg = 0; reg < 4; ++reg) {
            int orow = m0 + q * 4 + reg;
            if (orow < NA)
                io[(size_t)orow * NF + nt * 16 + r] = sspf(acc[nt][reg] + bia);
        }
    }
}

extern "C" void kernel_launch(void* const* d_in, const int* in_sizes, int n_in,
                              void* d_out, int out_size, void* d_ws, size_t ws_size,
                              hipStream_t stream)
{
    const float* x    = (const float*)d_in[0];
    const float* dR   = (const float*)d_in[1];
    const float* dRe  = (const float*)d_in[2];
    const float* mask = (const float*)d_in[3];
    const int*   nbr  = (const int*)d_in[4];
    const float* W1   = (const float*)d_in[5];
    const float* b1   = (const float*)d_in[6];
    const float* W2   = (const float*)d_in[7];
    const float* b2   = (const float*)d_in[8];
    const float* Wi2f = (const float*)d_in[9];
    const float* Wf2o = (const float*)d_in[10];
    const float* bf2o = (const float*)d_in[11];
    float* out = (float*)d_out;

    unsigned short* wsb = (unsigned short*)d_ws;
    unsigned short* W1T    = wsb;            // 4096 elems
    unsigned short* W2T    = wsb + 4096;     // 16384 elems
    unsigned short* WiT    = wsb + 20480;    // 16384 elems
    unsigned short* WoT    = wsb + 36864;    // 16384 elems
    unsigned short* yfeatb = wsb + 53248;    // 1,280,000 elems

    prep_weights<<<208, 256, 0, stream>>>(W1, W2, Wi2f, Wf2o, wsb);
    in2f_mfma<<<157, 256, 0, stream>>>(x, WiT, yfeatb);
    cfconv_ppd<<<GRID_CF, 256, 0, stream>>>(dR, dRe, mask, nbr, b1, b2,
                                            W1T, W2T, yfeatb, out);
    f2out_mfma<<<157, 256, 0, stream>>>(WoT, bf2o, out);
}

// Round 12
// 245.072 us; speedup vs baseline: 2.3300x; 1.2180x over previous
//
#include <hip/hip_runtime.h>
#include <hip/hip_bf16.h>

// SchNet CFConv, MI355X gfx950 — round 15: r14 with the SCRATCH SPILL fixed.
// r14's 186us + 268MB FETCH + 317MB WRITE = float fv[3][8] (memcpy-filled,
// live across stage2) allocated in SCRATCH -> 245MB/iter-set of spill traffic
// through HBM (rule: memcpy'd / addressable local arrays go to scratch).
// Fix: three NAMED f32x8 ext_vectors filled by fully-unrolled static-index
// scalar loads (no memcpy, no addressable array) -> guaranteed VGPRs.
// Everything else identical to r14: r6 scaffolding (prep_weights / in2f
// global-WiT / f2out, rest=89.5us proven) + r11 pipelined persistent cfconv
// structure (73us proven with register staging).
//
// d_ws layout (unsigned short elements):
//   [0      .. 4096  )  W1T  bf16 [128 f][32 gpad]   (g>=25 zero)
//   [4096   .. 20480 )  W2T  bf16 [128 h][128 j]
//   [20480  .. 36864 )  WiT  bf16 [128 f][128 i]
//   [36864  .. 53248 )  WoT  bf16 [128 o][128 f]
//   [53248  .. +1.28M)  yfeatb bf16 [10000][128]

#define NA 10000
#define NK 48
#define NF 128
#define HP  136   // s_H  row pad (bf16): 272 B rows -> 2-way (free)
#define YFP 136   // s_yf row pad (bf16)
#define GRID_CF 1024

typedef __bf16 bf16x8 __attribute__((ext_vector_type(8)));
typedef float  f32x4  __attribute__((ext_vector_type(4)));
typedef float  f32x8  __attribute__((ext_vector_type(8)));

__device__ __forceinline__ unsigned short f2bs(float x) {
    return __builtin_bit_cast(unsigned short, (__bf16)x);
}
__device__ __forceinline__ float bs2f(unsigned short u) {
    return (float)__builtin_bit_cast(__bf16, u);
}
__device__ __forceinline__ float sspf(float v) {
    return fmaxf(v, 0.0f) + __logf(1.0f + __expf(-fabsf(v))) - 0.69314718056f;
}

// ---- kernel 1: transpose-convert weights to bf16 in d_ws (r6-proven) ----
__global__ __launch_bounds__(256) void prep_weights(
    const float* __restrict__ W1,
    const float* __restrict__ W2,
    const float* __restrict__ Wi,
    const float* __restrict__ Wo,
    unsigned short* __restrict__ wsb)
{
    int i = blockIdx.x * 256 + threadIdx.x;
    if (i < 4096) {                       // W1T[f][g], g padded to 32
        int f = i >> 5, g = i & 31;
        wsb[i] = (g < 25) ? f2bs(W1[g * NF + f]) : (unsigned short)0;
    } else if (i < 20480) {               // W2T[h][j]
        int j = i - 4096; int h = j >> 7, k = j & 127;
        wsb[i] = f2bs(W2[k * NF + h]);
    } else if (i < 36864) {               // WiT[f][i]
        int j = i - 20480; int f = j >> 7, k = j & 127;
        wsb[i] = f2bs(Wi[k * NF + f]);
    } else if (i < 53248) {               // WoT[o][f]
        int j = i - 36864; int f = j >> 7, k = j & 127;
        wsb[i] = f2bs(Wo[k * NF + f]);
    }
}

// ---- kernel 2: in2f yfeatb = bf16(x @ W_in2f), global-WiT MFMA (r6-proven) ----
__global__ __launch_bounds__(256) void in2f_mfma(
    const float* __restrict__ x,
    const unsigned short* __restrict__ WiT,
    unsigned short* __restrict__ yfeatb)
{
    const int tid = threadIdx.x;
    const int w = tid >> 6;
    const int lane = tid & 63;
    const int r = lane & 15;
    const int q = lane >> 4;
    const int m0 = blockIdx.x * 64 + w * 16;
    const int row = m0 + r;
    const bool rv = (row < NA);

    f32x4 acc[8];
    #pragma unroll
    for (int nt = 0; nt < 8; ++nt) { acc[nt][0]=0.f; acc[nt][1]=0.f; acc[nt][2]=0.f; acc[nt][3]=0.f; }

    #pragma unroll
    for (int ks = 0; ks < 4; ++ks) {
        bf16x8 a;
        if (rv) {
            const float4* xp = (const float4*)(x + (size_t)row * NF + ks * 32 + q * 8);
            float4 v0 = xp[0], v1 = xp[1];
            a[0]=(__bf16)v0.x; a[1]=(__bf16)v0.y; a[2]=(__bf16)v0.z; a[3]=(__bf16)v0.w;
            a[4]=(__bf16)v1.x; a[5]=(__bf16)v1.y; a[6]=(__bf16)v1.z; a[7]=(__bf16)v1.w;
        } else {
            #pragma unroll
            for (int j = 0; j < 8; ++j) a[j] = (__bf16)0.0f;
        }
        #pragma unroll
        for (int nt = 0; nt < 8; ++nt) {
            bf16x8 b = *(const bf16x8*)(WiT + (nt * 16 + r) * NF + ks * 32 + q * 8);
            acc[nt] = __builtin_amdgcn_mfma_f32_16x16x32_bf16(a, b, acc[nt], 0, 0, 0);
        }
    }
    #pragma unroll
    for (int nt = 0; nt < 8; ++nt) {
        #pragma unroll
        for (int reg = 0; reg < 4; ++reg) {
            int orow = m0 + q * 4 + reg;
            if (orow < NA)
                yfeatb[(size_t)orow * NF + nt * 16 + r] = f2bs(acc[nt][reg]);
        }
    }
}

// ---- kernel 3: pipelined persistent cfconv, direct dRe, REGISTER staging ----
__global__ __launch_bounds__(256, 4) void cfconv_ppd(
    const float* __restrict__ dR,
    const float* __restrict__ dRe,
    const float* __restrict__ mask,
    const int*   __restrict__ nbr,
    const float* __restrict__ b1,
    const float* __restrict__ b2,
    const unsigned short* __restrict__ W1T,
    const unsigned short* __restrict__ W2T,
    const unsigned short* __restrict__ yfeatb,
    float* __restrict__ yout)
{
    __shared__ __align__(16) unsigned short s_H[NK * HP];    // 13056 B
    __shared__ __align__(16) unsigned short s_yf[NK * YFP];  // 13056 B
    __shared__ float s_cm[NK];                               // 192 B

    const int tid = threadIdx.x;
    const int w = tid >> 6;
    const int lane = tid & 63;
    const int r = lane & 15;
    const int q = lane >> 4;
    const int nt0 = w * 2;
    const int kb = tid >> 4;
    const int sp = tid & 15;

    // ---- hoisted weights/biases (amortized over ~10 atoms) ----
    const bf16x8 bfr0 = *(const bf16x8*)(W1T + ((nt0    ) * 16 + r) * 32 + q * 8);
    const bf16x8 bfr1 = *(const bf16x8*)(W1T + ((nt0 + 1) * 16 + r) * 32 + q * 8);
    bf16x8 bw[2][4];
    #pragma unroll
    for (int t = 0; t < 2; ++t)
        #pragma unroll
        for (int ks = 0; ks < 4; ++ks)
            bw[t][ks] = *(const bf16x8*)(W2T + ((nt0 + t) * 16 + r) * NF + ks * 32 + q * 8);
    const float bias1a = b1[nt0 * 16 + r];
    const float bias1b = b1[nt0 * 16 + 16 + r];
    const float bias2a = b2[nt0 * 16 + r];
    const float bias2b = b2[nt0 * 16 + 16 + r];

    // ---- pipeline registers: NAMED ext_vectors only (no addressable arrays) ----
    bf16x8 g0, g1, g2;          // gathered neighbor rows (next atom)
    f32x8  fva, fvb, fvc;       // raw dRe floats (next atom), 24 VGPR, static idx
    float dv = 10.0f, mv = 0.0f;
    unsigned short hsv[24];     // stage1 output bf16 bits (static idx only)

    const bool qlt3 = (q < 3);

    // prefetch: issue ALL of next atom's global loads; scalar loads land in
    // named vector elements with compile-time indices -> guaranteed VGPRs.
    auto prefetch = [&](int nn) {
        const int nb0 = nbr[nn * NK + kb] * NF;
        const int nb1 = nbr[nn * NK + kb + 16] * NF;
        const int nb2 = nbr[nn * NK + kb + 32] * NF;
        g0 = *(const bf16x8*)(yfeatb + nb0 + sp * 8);
        g1 = *(const bf16x8*)(yfeatb + nb1 + sp * 8);
        g2 = *(const bf16x8*)(yfeatb + nb2 + sp * 8);
        const float* dre_n = dRe + (size_t)nn * (NK * 25);
        if (qlt3) {
            const float* p0 = dre_n + (     r) * 25 + q * 8;
            const float* p1 = dre_n + (16 + r) * 25 + q * 8;
            const float* p2 = dre_n + (32 + r) * 25 + q * 8;
            #pragma unroll
            for (int j = 0; j < 8; ++j) {
                fva[j] = p0[j];
                fvb[j] = p1[j];
                fvc[j] = p2[j];
            }
        } else {
            fva[0] = dre_n[(     r) * 25 + 24];
            fvb[0] = dre_n[(16 + r) * 25 + 24];
            fvc[0] = dre_n[(32 + r) * 25 + 24];
        }
        if (tid < NK) {
            dv = dR[nn * NK + tid];
            mv = mask[nn * NK + tid];
        }
    };

    // stage1: cvt floats -> bf16 A-frags (static select), MFMA vs W1, ssp -> hsv
    auto stage1 = [&]() {
        #pragma unroll
        for (int mt = 0; mt < 3; ++mt) {
            f32x8 fvv = (mt == 0) ? fva : (mt == 1) ? fvb : fvc;
            bf16x8 av8;
            if (qlt3) {
                #pragma unroll
                for (int j = 0; j < 8; ++j) av8[j] = (__bf16)fvv[j];
            } else {
                av8[0] = (__bf16)fvv[0];
                #pragma unroll
                for (int j = 1; j < 8; ++j) av8[j] = (__bf16)0.0f;
            }
            f32x4 zf; zf[0]=0.f; zf[1]=0.f; zf[2]=0.f; zf[3]=0.f;
            f32x4 h0v = __builtin_amdgcn_mfma_f32_16x16x32_bf16(av8, bfr0, zf, 0, 0, 0);
            f32x4 h1v = __builtin_amdgcn_mfma_f32_16x16x32_bf16(av8, bfr1, zf, 0, 0, 0);
            #pragma unroll
            for (int reg = 0; reg < 4; ++reg) {
                hsv[mt * 8 + reg]     = f2bs(sspf(h0v[reg] + bias1a));
                hsv[mt * 8 + 4 + reg] = f2bs(sspf(h1v[reg] + bias1b));
            }
        }
    };

    auto ldswrite = [&]() {
        #pragma unroll
        for (int mt = 0; mt < 3; ++mt) {
            #pragma unroll
            for (int reg = 0; reg < 4; ++reg) {
                int k = mt * 16 + q * 4 + reg;
                s_H[k * HP + nt0 * 16 + r]      = hsv[mt * 8 + reg];
                s_H[k * HP + nt0 * 16 + 16 + r] = hsv[mt * 8 + 4 + reg];
            }
        }
        *(bf16x8*)(&s_yf[(kb     ) * YFP + sp * 8]) = g0;
        *(bf16x8*)(&s_yf[(kb + 16) * YFP + sp * 8]) = g1;
        *(bf16x8*)(&s_yf[(kb + 32) * YFP + sp * 8]) = g2;
        if (tid < NK)
            s_cm[tid] = (dv <= 5.0f) ? mv : 0.0f;
    };

    // ---- prologue: fill pipeline for first atom ----
    int n = blockIdx.x;
    prefetch(n);
    stage1();
    ldswrite();
    __syncthreads();   // barrier A(0)

    while (true) {
        const int n_next = n + GRID_CF;
        const bool more = (n_next < NA);

        if (more) prefetch(n_next);   // issue next atom's globals early

        // ---- stage 2 for atom n: A2 = H @ W2 ----
        f32x4 acc[3][2];
        #pragma unroll
        for (int mt = 0; mt < 3; ++mt)
            #pragma unroll
            for (int t = 0; t < 2; ++t) { acc[mt][t][0]=0.f; acc[mt][t][1]=0.f; acc[mt][t][2]=0.f; acc[mt][t][3]=0.f; }

        #pragma unroll
        for (int ks = 0; ks < 4; ++ks) {
            #pragma unroll
            for (int mt = 0; mt < 3; ++mt) {
                bf16x8 ah = *(const bf16x8*)(&s_H[(mt * 16 + r) * HP + ks * 32 + q * 8]);
                acc[mt][0] = __builtin_amdgcn_mfma_f32_16x16x32_bf16(ah, bw[0][ks], acc[mt][0], 0, 0, 0);
                acc[mt][1] = __builtin_amdgcn_mfma_f32_16x16x32_bf16(ah, bw[1][ks], acc[mt][1], 0, 0, 0);
            }
        }

        if (more) stage1();           // next atom's stage1 (reg-only, overlaps)

        // ---- aggregation for atom n ----
        float part0 = 0.f, part1 = 0.f;
        const int h0 = nt0 * 16 + r;
        #pragma unroll
        for (int mt = 0; mt < 3; ++mt) {
            #pragma unroll
            for (int reg = 0; reg < 4; ++reg) {
                int k = mt * 16 + q * 4 + reg;
                float cmk = s_cm[k];
                part0 += cmk * (acc[mt][0][reg] + bias2a) * bs2f(s_yf[k * YFP + h0]);
                part1 += cmk * (acc[mt][1][reg] + bias2b) * bs2f(s_yf[k * YFP + h0 + 16]);
            }
        }
        part0 += __shfl_xor(part0, 16);
        part0 += __shfl_xor(part0, 32);
        part1 += __shfl_xor(part1, 16);
        part1 += __shfl_xor(part1, 32);
        if (q == 0) {
            yout[(size_t)n * NF + h0]      = part0;
            yout[(size_t)n * NF + h0 + 16] = part1;
        }

        if (!more) break;

        __syncthreads();   // barrier B: all reads of s_H/s_yf/s_cm done
        ldswrite();        // exchange window: dump next atom to LDS
        __syncthreads();   // barrier A: next atom's LDS ready
        n = n_next;
    }
}

// ---- kernel 4: f2out = ssp(y @ Wf2o + b), MFMA, IN PLACE on out (r6-proven) ----
__global__ __launch_bounds__(256) void f2out_mfma(
    const unsigned short* __restrict__ WoT,
    const float* __restrict__ bo,
    float* io)
{
    const int tid = threadIdx.x;
    const int w = tid >> 6;
    const int lane = tid & 63;
    const int r = lane & 15;
    const int q = lane >> 4;
    const int m0 = blockIdx.x * 64 + w * 16;
    const int row = m0 + r;
    const bool rv = (row < NA);

    f32x4 acc[8];
    #pragma unroll
    for (int nt = 0; nt < 8; ++nt) { acc[nt][0]=0.f; acc[nt][1]=0.f; acc[nt][2]=0.f; acc[nt][3]=0.f; }

    #pragma unroll
    for (int ks = 0; ks < 4; ++ks) {
        bf16x8 a;
        if (rv) {
            const float4* yp = (const float4*)(io + (size_t)row * NF + ks * 32 + q * 8);
            float4 v0 = yp[0], v1 = yp[1];
            a[0]=(__bf16)v0.x; a[1]=(__bf16)v0.y; a[2]=(__bf16)v0.z; a[3]=(__bf16)v0.w;
            a[4]=(__bf16)v1.x; a[5]=(__bf16)v1.y; a[6]=(__bf16)v1.z; a[7]=(__bf16)v1.w;
        } else {
            #pragma unroll
            for (int j = 0; j < 8; ++j) a[j] = (__bf16)0.0f;
        }
        #pragma unroll
        for (int nt = 0; nt < 8; ++nt) {
            bf16x8 b = *(const bf16x8*)(WoT + (nt * 16 + r) * NF + ks * 32 + q * 8);
            acc[nt] = __builtin_amdgcn_mfma_f32_16x16x32_bf16(a, b, acc[nt], 0, 0, 0);
        }
    }
    #pragma unroll
    for (int nt = 0; nt < 8; ++nt) {
        float bia = bo[nt * 16 + r];
        #pragma unroll
        for (int reg = 0; reg < 4; ++reg) {
            int orow = m0 + q * 4 + reg;
            if (orow < NA)
                io[(size_t)orow * NF + nt * 16 + r] = sspf(acc[nt][reg] + bia);
        }
    }
}

extern "C" void kernel_launch(void* const* d_in, const int* in_sizes, int n_in,
                              void* d_out, int out_size, void* d_ws, size_t ws_size,
                              hipStream_t stream)
{
    const float* x    = (const float*)d_in[0];
    const float* dR   = (const float*)d_in[1];
    const float* dRe  = (const float*)d_in[2];
    const float* mask = (const float*)d_in[3];
    const int*   nbr  = (const int*)d_in[4];
    const float* W1   = (const float*)d_in[5];
    const float* b1   = (const float*)d_in[6];
    const float* W2   = (const float*)d_in[7];
    const float* b2   = (const float*)d_in[8];
    const float* Wi2f = (const float*)d_in[9];
    const float* Wf2o = (const float*)d_in[10];
    const float* bf2o = (const float*)d_in[11];
    float* out = (float*)d_out;

    unsigned short* wsb = (unsigned short*)d_ws;
    unsigned short* W1T    = wsb;            // 4096 elems
    unsigned short* W2T    = wsb + 4096;     // 16384 elems
    unsigned short* WiT    = wsb + 20480;    // 16384 elems
    unsigned short* WoT    = wsb + 36864;    // 16384 elems
    unsigned short* yfeatb = wsb + 53248;    // 1,280,000 elems

    prep_weights<<<208, 256, 0, stream>>>(W1, W2, Wi2f, Wf2o, wsb);
    in2f_mfma<<<157, 256, 0, stream>>>(x, WiT, yfeatb);
    cfconv_ppd<<<GRID_CF, 256, 0, stream>>>(dR, dRe, mask, nbr, b1, b2,
                                            W1T, W2T, yfeatb, out);
    f2out_mfma<<<157, 256, 0, stream>>>(WoT, bf2o, out);
}

// Round 13
// 181.950 us; speedup vs baseline: 3.1383x; 1.3469x over previous
//
#include <hip/hip_runtime.h>
#include <hip/hip_bf16.h>

// SchNet CFConv, MI355X gfx950 — round 16: r15 with the REGISTER BUDGET fixed.
// r15 halved the spill but WRITE was still 163MB: live pipeline state
// (bw 32 + bfr 8 + g 12 + fva-c 24 + hsv 12 + acc 24 + misc ~25 ≈ 140 VGPR)
// exceeds the __launch_bounds__(256,4) cap of 512/4 = 128 -> allocator spills
// the pipeline registers every iteration. Fix: __launch_bounds__(256,3)
// (cap 170 >= demand ~140) + grid 768 = 3 blocks/CU, all co-resident (grid
// must not exceed guaranteed residency or a straggler block serializes).
// hsv also moved to three named ushort8 vectors (static idx, guaranteed VGPR).
// Everything else byte-identical to r15 (r6 scaffolding + r11 pipeline).
//
// d_ws layout (unsigned short elements):
//   [0      .. 4096  )  W1T  bf16 [128 f][32 gpad]   (g>=25 zero)
//   [4096   .. 20480 )  W2T  bf16 [128 h][128 j]
//   [20480  .. 36864 )  WiT  bf16 [128 f][128 i]
//   [36864  .. 53248 )  WoT  bf16 [128 o][128 f]
//   [53248  .. +1.28M)  yfeatb bf16 [10000][128]

#define NA 10000
#define NK 48
#define NF 128
#define HP  136   // s_H  row pad (bf16): 272 B rows -> 2-way (free)
#define YFP 136   // s_yf row pad (bf16)
#define GRID_CF 768   // 3 blocks/CU x 256 CU, matches launch_bounds(256,3)

typedef __bf16 bf16x8 __attribute__((ext_vector_type(8)));
typedef float  f32x4  __attribute__((ext_vector_type(4)));
typedef float  f32x8  __attribute__((ext_vector_type(8)));
typedef unsigned short u16x8 __attribute__((ext_vector_type(8)));

__device__ __forceinline__ unsigned short f2bs(float x) {
    return __builtin_bit_cast(unsigned short, (__bf16)x);
}
__device__ __forceinline__ float bs2f(unsigned short u) {
    return (float)__builtin_bit_cast(__bf16, u);
}
__device__ __forceinline__ float sspf(float v) {
    return fmaxf(v, 0.0f) + __logf(1.0f + __expf(-fabsf(v))) - 0.69314718056f;
}

// ---- kernel 1: transpose-convert weights to bf16 in d_ws (r6-proven) ----
__global__ __launch_bounds__(256) void prep_weights(
    const float* __restrict__ W1,
    const float* __restrict__ W2,
    const float* __restrict__ Wi,
    const float* __restrict__ Wo,
    unsigned short* __restrict__ wsb)
{
    int i = blockIdx.x * 256 + threadIdx.x;
    if (i < 4096) {                       // W1T[f][g], g padded to 32
        int f = i >> 5, g = i & 31;
        wsb[i] = (g < 25) ? f2bs(W1[g * NF + f]) : (unsigned short)0;
    } else if (i < 20480) {               // W2T[h][j]
        int j = i - 4096; int h = j >> 7, k = j & 127;
        wsb[i] = f2bs(W2[k * NF + h]);
    } else if (i < 36864) {               // WiT[f][i]
        int j = i - 20480; int f = j >> 7, k = j & 127;
        wsb[i] = f2bs(Wi[k * NF + f]);
    } else if (i < 53248) {               // WoT[o][f]
        int j = i - 36864; int f = j >> 7, k = j & 127;
        wsb[i] = f2bs(Wo[k * NF + f]);
    }
}

// ---- kernel 2: in2f yfeatb = bf16(x @ W_in2f), global-WiT MFMA (r6-proven) ----
__global__ __launch_bounds__(256) void in2f_mfma(
    const float* __restrict__ x,
    const unsigned short* __restrict__ WiT,
    unsigned short* __restrict__ yfeatb)
{
    const int tid = threadIdx.x;
    const int w = tid >> 6;
    const int lane = tid & 63;
    const int r = lane & 15;
    const int q = lane >> 4;
    const int m0 = blockIdx.x * 64 + w * 16;
    const int row = m0 + r;
    const bool rv = (row < NA);

    f32x4 acc[8];
    #pragma unroll
    for (int nt = 0; nt < 8; ++nt) { acc[nt][0]=0.f; acc[nt][1]=0.f; acc[nt][2]=0.f; acc[nt][3]=0.f; }

    #pragma unroll
    for (int ks = 0; ks < 4; ++ks) {
        bf16x8 a;
        if (rv) {
            const float4* xp = (const float4*)(x + (size_t)row * NF + ks * 32 + q * 8);
            float4 v0 = xp[0], v1 = xp[1];
            a[0]=(__bf16)v0.x; a[1]=(__bf16)v0.y; a[2]=(__bf16)v0.z; a[3]=(__bf16)v0.w;
            a[4]=(__bf16)v1.x; a[5]=(__bf16)v1.y; a[6]=(__bf16)v1.z; a[7]=(__bf16)v1.w;
        } else {
            #pragma unroll
            for (int j = 0; j < 8; ++j) a[j] = (__bf16)0.0f;
        }
        #pragma unroll
        for (int nt = 0; nt < 8; ++nt) {
            bf16x8 b = *(const bf16x8*)(WiT + (nt * 16 + r) * NF + ks * 32 + q * 8);
            acc[nt] = __builtin_amdgcn_mfma_f32_16x16x32_bf16(a, b, acc[nt], 0, 0, 0);
        }
    }
    #pragma unroll
    for (int nt = 0; nt < 8; ++nt) {
        #pragma unroll
        for (int reg = 0; reg < 4; ++reg) {
            int orow = m0 + q * 4 + reg;
            if (orow < NA)
                yfeatb[(size_t)orow * NF + nt * 16 + r] = f2bs(acc[nt][reg]);
        }
    }
}

// ---- kernel 3: pipelined persistent cfconv, direct dRe, register staging ----
__global__ __launch_bounds__(256, 3) void cfconv_ppd(
    const float* __restrict__ dR,
    const float* __restrict__ dRe,
    const float* __restrict__ mask,
    const int*   __restrict__ nbr,
    const float* __restrict__ b1,
    const float* __restrict__ b2,
    const unsigned short* __restrict__ W1T,
    const unsigned short* __restrict__ W2T,
    const unsigned short* __restrict__ yfeatb,
    float* __restrict__ yout)
{
    __shared__ __align__(16) unsigned short s_H[NK * HP];    // 13056 B
    __shared__ __align__(16) unsigned short s_yf[NK * YFP];  // 13056 B
    __shared__ float s_cm[NK];                               // 192 B

    const int tid = threadIdx.x;
    const int w = tid >> 6;
    const int lane = tid & 63;
    const int r = lane & 15;
    const int q = lane >> 4;
    const int nt0 = w * 2;
    const int kb = tid >> 4;
    const int sp = tid & 15;

    // ---- hoisted weights/biases (amortized over ~13 atoms) ----
    const bf16x8 bfr0 = *(const bf16x8*)(W1T + ((nt0    ) * 16 + r) * 32 + q * 8);
    const bf16x8 bfr1 = *(const bf16x8*)(W1T + ((nt0 + 1) * 16 + r) * 32 + q * 8);
    bf16x8 bw[2][4];
    #pragma unroll
    for (int t = 0; t < 2; ++t)
        #pragma unroll
        for (int ks = 0; ks < 4; ++ks)
            bw[t][ks] = *(const bf16x8*)(W2T + ((nt0 + t) * 16 + r) * NF + ks * 32 + q * 8);
    const float bias1a = b1[nt0 * 16 + r];
    const float bias1b = b1[nt0 * 16 + 16 + r];
    const float bias2a = b2[nt0 * 16 + r];
    const float bias2b = b2[nt0 * 16 + 16 + r];

    // ---- pipeline registers: NAMED ext_vectors only ----
    bf16x8 g0, g1, g2;          // gathered neighbor rows (next atom)
    f32x8  fva, fvb, fvc;       // raw dRe floats (next atom), static idx
    u16x8  hsv0, hsv1, hsv2;    // stage1 output bf16 bits (named, static idx)
    float dv = 10.0f, mv = 0.0f;

    const bool qlt3 = (q < 3);

    auto prefetch = [&](int nn) {
        const int nb0 = nbr[nn * NK + kb] * NF;
        const int nb1 = nbr[nn * NK + kb + 16] * NF;
        const int nb2 = nbr[nn * NK + kb + 32] * NF;
        g0 = *(const bf16x8*)(yfeatb + nb0 + sp * 8);
        g1 = *(const bf16x8*)(yfeatb + nb1 + sp * 8);
        g2 = *(const bf16x8*)(yfeatb + nb2 + sp * 8);
        const float* dre_n = dRe + (size_t)nn * (NK * 25);
        if (qlt3) {
            const float* p0 = dre_n + (     r) * 25 + q * 8;
            const float* p1 = dre_n + (16 + r) * 25 + q * 8;
            const float* p2 = dre_n + (32 + r) * 25 + q * 8;
            #pragma unroll
            for (int j = 0; j < 8; ++j) {
                fva[j] = p0[j];
                fvb[j] = p1[j];
                fvc[j] = p2[j];
            }
        } else {
            fva[0] = dre_n[(     r) * 25 + 24];
            fvb[0] = dre_n[(16 + r) * 25 + 24];
            fvc[0] = dre_n[(32 + r) * 25 + 24];
        }
        if (tid < NK) {
            dv = dR[nn * NK + tid];
            mv = mask[nn * NK + tid];
        }
    };

    // stage1 for one mt: cvt floats -> bf16 A-frag, 2 MFMA, ssp -> named hsv vec
#define STAGE1_MT(FVV, HSV)                                                     \
    {                                                                           \
        bf16x8 av8;                                                             \
        if (qlt3) {                                                             \
            _Pragma("unroll")                                                   \
            for (int j = 0; j < 8; ++j) av8[j] = (__bf16)FVV[j];                \
        } else {                                                                \
            av8[0] = (__bf16)FVV[0];                                            \
            _Pragma("unroll")                                                   \
            for (int j = 1; j < 8; ++j) av8[j] = (__bf16)0.0f;                  \
        }                                                                       \
        f32x4 zf; zf[0]=0.f; zf[1]=0.f; zf[2]=0.f; zf[3]=0.f;                   \
        f32x4 h0v = __builtin_amdgcn_mfma_f32_16x16x32_bf16(av8, bfr0, zf, 0, 0, 0); \
        f32x4 h1v = __builtin_amdgcn_mfma_f32_16x16x32_bf16(av8, bfr1, zf, 0, 0, 0); \
        _Pragma("unroll")                                                       \
        for (int reg = 0; reg < 4; ++reg) {                                     \
            HSV[reg]     = f2bs(sspf(h0v[reg] + bias1a));                       \
            HSV[4 + reg] = f2bs(sspf(h1v[reg] + bias1b));                       \
        }                                                                       \
    }

    auto stage1 = [&]() {
        STAGE1_MT(fva, hsv0)
        STAGE1_MT(fvb, hsv1)
        STAGE1_MT(fvc, hsv2)
    };

#define LDSW_MT(MT, HSV)                                                        \
    {                                                                           \
        _Pragma("unroll")                                                       \
        for (int reg = 0; reg < 4; ++reg) {                                     \
            int k = MT * 16 + q * 4 + reg;                                      \
            s_H[k * HP + nt0 * 16 + r]      = HSV[reg];                         \
            s_H[k * HP + nt0 * 16 + 16 + r] = HSV[4 + reg];                     \
        }                                                                       \
    }

    auto ldswrite = [&]() {
        LDSW_MT(0, hsv0)
        LDSW_MT(1, hsv1)
        LDSW_MT(2, hsv2)
        *(bf16x8*)(&s_yf[(kb     ) * YFP + sp * 8]) = g0;
        *(bf16x8*)(&s_yf[(kb + 16) * YFP + sp * 8]) = g1;
        *(bf16x8*)(&s_yf[(kb + 32) * YFP + sp * 8]) = g2;
        if (tid < NK)
            s_cm[tid] = (dv <= 5.0f) ? mv : 0.0f;
    };

    // ---- prologue: fill pipeline for first atom ----
    int n = blockIdx.x;
    prefetch(n);
    stage1();
    ldswrite();
    __syncthreads();   // barrier A(0)

    while (true) {
        const int n_next = n + GRID_CF;
        const bool more = (n_next < NA);

        if (more) prefetch(n_next);   // issue next atom's globals early

        // ---- stage 2 for atom n: A2 = H @ W2 ----
        f32x4 acc[3][2];
        #pragma unroll
        for (int mt = 0; mt < 3; ++mt)
            #pragma unroll
            for (int t = 0; t < 2; ++t) { acc[mt][t][0]=0.f; acc[mt][t][1]=0.f; acc[mt][t][2]=0.f; acc[mt][t][3]=0.f; }

        #pragma unroll
        for (int ks = 0; ks < 4; ++ks) {
            #pragma unroll
            for (int mt = 0; mt < 3; ++mt) {
                bf16x8 ah = *(const bf16x8*)(&s_H[(mt * 16 + r) * HP + ks * 32 + q * 8]);
                acc[mt][0] = __builtin_amdgcn_mfma_f32_16x16x32_bf16(ah, bw[0][ks], acc[mt][0], 0, 0, 0);
                acc[mt][1] = __builtin_amdgcn_mfma_f32_16x16x32_bf16(ah, bw[1][ks], acc[mt][1], 0, 0, 0);
            }
        }

        if (more) stage1();           // next atom's stage1 (reg-only, overlaps)

        // ---- aggregation for atom n ----
        float part0 = 0.f, part1 = 0.f;
        const int h0 = nt0 * 16 + r;
        #pragma unroll
        for (int mt = 0; mt < 3; ++mt) {
            #pragma unroll
            for (int reg = 0; reg < 4; ++reg) {
                int k = mt * 16 + q * 4 + reg;
                float cmk = s_cm[k];
                part0 += cmk * (acc[mt][0][reg] + bias2a) * bs2f(s_yf[k * YFP + h0]);
                part1 += cmk * (acc[mt][1][reg] + bias2b) * bs2f(s_yf[k * YFP + h0 + 16]);
            }
        }
        part0 += __shfl_xor(part0, 16);
        part0 += __shfl_xor(part0, 32);
        part1 += __shfl_xor(part1, 16);
        part1 += __shfl_xor(part1, 32);
        if (q == 0) {
            yout[(size_t)n * NF + h0]      = part0;
            yout[(size_t)n * NF + h0 + 16] = part1;
        }

        if (!more) break;

        __syncthreads();   // barrier B: all reads of s_H/s_yf/s_cm done
        ldswrite();        // exchange window: dump next atom to LDS
        __syncthreads();   // barrier A: next atom's LDS ready
        n = n_next;
    }
}

// ---- kernel 4: f2out = ssp(y @ Wf2o + b), MFMA, IN PLACE on out (r6-proven) ----
__global__ __launch_bounds__(256) void f2out_mfma(
    const unsigned short* __restrict__ WoT,
    const float* __restrict__ bo,
    float* io)
{
    const int tid = threadIdx.x;
    const int w = tid >> 6;
    const int lane = tid & 63;
    const int r = lane & 15;
    const int q = lane >> 4;
    const int m0 = blockIdx.x * 64 + w * 16;
    const int row = m0 + r;
    const bool rv = (row < NA);

    f32x4 acc[8];
    #pragma unroll
    for (int nt = 0; nt < 8; ++nt) { acc[nt][0]=0.f; acc[nt][1]=0.f; acc[nt][2]=0.f; acc[nt][3]=0.f; }

    #pragma unroll
    for (int ks = 0; ks < 4; ++ks) {
        bf16x8 a;
        if (rv) {
            const float4* yp = (const float4*)(io + (size_t)row * NF + ks * 32 + q * 8);
            float4 v0 = yp[0], v1 = yp[1];
            a[0]=(__bf16)v0.x; a[1]=(__bf16)v0.y; a[2]=(__bf16)v0.z; a[3]=(__bf16)v0.w;
            a[4]=(__bf16)v1.x; a[5]=(__bf16)v1.y; a[6]=(__bf16)v1.z; a[7]=(__bf16)v1.w;
        } else {
            #pragma unroll
            for (int j = 0; j < 8; ++j) a[j] = (__bf16)0.0f;
        }
        #pragma unroll
        for (int nt = 0; nt < 8; ++nt) {
            bf16x8 b = *(const bf16x8*)(WoT + (nt * 16 + r) * NF + ks * 32 + q * 8);
            acc[nt] = __builtin_amdgcn_mfma_f32_16x16x32_bf16(a, b, acc[nt], 0, 0, 0);
        }
    }
    #pragma unroll
    for (int nt = 0; nt < 8; ++nt) {
        float bia = bo[nt * 16 + r];
        #pragma unroll
        for (int reg = 0; reg < 4; ++reg) {
            int orow = m0 + q * 4 + reg;
            if (orow < NA)
                io[(size_t)orow * NF + nt * 16 + r] = sspf(acc[nt][reg] + bia);
        }
    }
}

extern "C" void kernel_launch(void* const* d_in, const int* in_sizes, int n_in,
                              void* d_out, int out_size, void* d_ws, size_t ws_size,
                              hipStream_t stream)
{
    const float* x    = (const float*)d_in[0];
    const float* dR   = (const float*)d_in[1];
    const float* dRe  = (const float*)d_in[2];
    const float* mask = (const float*)d_in[3];
    const int*   nbr  = (const int*)d_in[4];
    const float* W1   = (const float*)d_in[5];
    const float* b1   = (const float*)d_in[6];
    const float* W2   = (const float*)d_in[7];
    const float* b2   = (const float*)d_in[8];
    const float* Wi2f = (const float*)d_in[9];
    const float* Wf2o = (const float*)d_in[10];
    const float* bf2o = (const float*)d_in[11];
    float* out = (float*)d_out;

    unsigned short* wsb = (unsigned short*)d_ws;
    unsigned short* W1T    = wsb;            // 4096 elems
    unsigned short* W2T    = wsb + 4096;     // 16384 elems
    unsigned short* WiT    = wsb + 20480;    // 16384 elems
    unsigned short* WoT    = wsb + 36864;    // 16384 elems
    unsigned short* yfeatb = wsb + 53248;    // 1,280,000 elems

    prep_weights<<<208, 256, 0, stream>>>(W1, W2, Wi2f, Wf2o, wsb);
    in2f_mfma<<<157, 256, 0, stream>>>(x, WiT, yfeatb);
    cfconv_ppd<<<GRID_CF, 256, 0, stream>>>(dR, dRe, mask, nbr, b1, b2,
                                            W1T, W2T, yfeatb, out);
    f2out_mfma<<<157, 256, 0, stream>>>(WoT, bf2o, out);
}